// Round 10
// baseline (246.615 us; speedup 1.0000x reference)
//
#include <hip/hip_runtime.h>
#include <math.h>

// ---------------------------------------------------------------------------
// AttentionEncoder: B=8, S=2048, D=1024, K=64
// Round 10: gemm256 moved to mfma_f32_32x32x16_bf16 (2495 TF ceiling vs 2075,
// half the instructions). LDS [256][64] full-row tiles, 8-slot XOR swizzle
// (2-way = free), linear gll dest + pre-swizzled source. R6 sync discipline:
// 4 phases/K-tile (one 16-k sub each), pre-barrier reads, stage burst at P1,
// vmcnt(0) at P4. LN kernels: wave-per-row (no block barriers).
// ---------------------------------------------------------------------------

typedef __bf16 bf16_t;
typedef __bf16 bf16x4_t __attribute__((ext_vector_type(4)));
typedef __bf16 bf16x8_t __attribute__((ext_vector_type(8)));
typedef float  f32x4    __attribute__((ext_vector_type(4)));
typedef float  f32x16   __attribute__((ext_vector_type(16)));

#define DEV static __device__ __forceinline__

DEV void gll16(const void* g, void* l) {
  __builtin_amdgcn_global_load_lds(
      (const __attribute__((address_space(1))) void*)g,
      (__attribute__((address_space(3))) void*)l, 16, 0, 0);
}

// ---------------------------------------------------------------------------
// 256x256 tile, BK=64, 512 threads (8 waves 2Mx4N, wave tile 128x64), dbuf.
// 32x32x16 MFMA: per wave 4 m-frags x 2 n-frags, acc f32x16 each (128 VGPR).
// MODE: 1 VT (bf16, +bv[row]) ; 3 ATTN (bf16) ; 4 FF (bf16, relu(+b1[col]))
// ---------------------------------------------------------------------------
template <int MODE, int MFAST>
__global__ __launch_bounds__(512, 2) void gemm256(
    const bf16_t* __restrict__ A, const bf16_t* __restrict__ B,
    bf16_t* __restrict__ C, int K, int lda, int ldb, int ldc,
    long sAb, long sBb, long sCb, const float* __restrict__ aux0) {
  const int gx = gridDim.x, gy = gridDim.y;
  const int gxy = gx * gy;
  const int nwg = gxy * (int)gridDim.z;
  const int orig = blockIdx.x + gx * blockIdx.y + gxy * blockIdx.z;
  const int lid = (orig & 7) * (nwg >> 3) + (orig >> 3);
  const int bz = lid / gxy;
  const int rem = lid - bz * gxy;
  const int bx = MFAST ? (rem / gy) : (rem % gx);
  const int by = MFAST ? (rem % gy) : (rem / gx);

  A += (long)bz * sAb;
  B += (long)bz * sBb;
  const int m0 = by * 256, n0 = bx * 256;

  // As: 2 bufs x [256][64] (32KB each); Bs likewise. 128KB total.
  __shared__ bf16_t SM[65536];
#define ASH(b) (&SM[(b) << 14])
#define BSH(b) (&SM[32768 + ((b) << 14)])

  const int tid = threadIdx.x;
  const int wid = tid >> 6, l = tid & 63;
  const int wr = wid >> 2, wc = wid & 3;   // 2x4 wave grid; wave tile 128x64
  const int ln31 = l & 31, hi = l >> 5;

  // staging: thread tid -> LDS row tid>>3 (+64 per extra load), phys slot
  // tid&7 (LINEAR dest = tid*16B). Source fetches LOGICAL slot
  // (tid&7)^((tid>>3)&7); row&7 invariant under +64-row loads.
  const int sRow = tid >> 3;
  const int sSl = ((tid & 7) ^ ((tid >> 3) & 7)) << 3;
  const bf16_t* Asrc = A + (long)(m0 + sRow) * lda + sSl;
  const bf16_t* Bsrc = B + (long)(n0 + sRow) * ldb + sSl;
  const long aStep = (long)64 * lda, bStep = (long)64 * ldb;

#define STAGE_A(b, kt) do { \
    const bf16_t* s_ = Asrc + (long)(kt) * 64; \
    gll16(s_,             ASH(b) + tid * 8); \
    gll16(s_ + aStep,     ASH(b) + 4096 + tid * 8); \
    gll16(s_ + 2 * aStep, ASH(b) + 8192 + tid * 8); \
    gll16(s_ + 3 * aStep, ASH(b) + 12288 + tid * 8); } while (0)
#define STAGE_B(b, kt) do { \
    const bf16_t* s_ = Bsrc + (long)(kt) * 64; \
    gll16(s_,             BSH(b) + tid * 8); \
    gll16(s_ + bStep,     BSH(b) + 4096 + tid * 8); \
    gll16(s_ + 2 * bStep, BSH(b) + 8192 + tid * 8); \
    gll16(s_ + 3 * bStep, BSH(b) + 12288 + tid * 8); } while (0)

  // read: frag row = base + (l&31); logical slot (kk<<1)|hi, phys ^ (l&7)
  const int aBase = (wr * 128 + ln31) * 64;   // + mf*2048 per m-frag
  const int bBase = (wc * 64 + ln31) * 64;    // + nf*2048 per n-frag

  f32x16 acc[4][2] = {};
  const int NT = K >> 6;

  STAGE_A(0, 0); STAGE_B(0, 0);
  asm volatile("s_waitcnt vmcnt(0)" ::: "memory");
  __builtin_amdgcn_s_barrier();

#define PHASE_SYNC() do { \
    __builtin_amdgcn_sched_barrier(0); \
    __builtin_amdgcn_s_barrier(); \
    asm volatile("s_waitcnt lgkmcnt(0)" ::: "memory"); \
    __builtin_amdgcn_sched_barrier(0); } while (0)

#define PHASE(kk, ...) do { \
    const int sl8 = ((((kk) << 1) | hi) ^ (l & 7)) << 3; \
    _Pragma("unroll") for (int nf = 0; nf < 2; ++nf) \
      bF[nf] = *(const bf16x8_t*)(BSH(p) + bBase + nf * 2048 + sl8); \
    _Pragma("unroll") for (int mf = 0; mf < 4; ++mf) \
      aF[mf] = *(const bf16x8_t*)(ASH(p) + aBase + mf * 2048 + sl8); \
    __VA_ARGS__; \
    PHASE_SYNC(); \
    __builtin_amdgcn_s_setprio(1); \
    _Pragma("unroll") for (int mf = 0; mf < 4; ++mf) \
    _Pragma("unroll") for (int nf = 0; nf < 2; ++nf) \
      acc[mf][nf] = __builtin_amdgcn_mfma_f32_32x32x16_bf16(aF[mf], bF[nf], acc[mf][nf], 0, 0, 0); \
    __builtin_amdgcn_s_setprio(0); } while (0)

  for (int t = 0; t < NT; ++t) {
    const int p = t & 1, q = p ^ 1;
    const bool pf = (t + 1 < NT);
    bf16x8_t aF[4], bF[2];

    PHASE(0, { if (pf) { STAGE_A(q, t + 1); STAGE_B(q, t + 1); } });
    PHASE(1, {});
    PHASE(2, {});
    PHASE(3, { asm volatile("s_waitcnt vmcnt(0)" ::: "memory"); });
  }
#undef STAGE_A
#undef STAGE_B
#undef PHASE_SYNC
#undef PHASE

  // epilogue: 32x32 C/D frag col=lane&31, row=(reg&3)+8*(reg>>2)+4*(lane>>5)
  bf16_t* Cb = C + (long)bz * sCb;
  const int rowb = m0 + wr * 128 + 4 * hi;
  const int colb = n0 + wc * 64 + ln31;
#pragma unroll
  for (int mf = 0; mf < 4; ++mf)
#pragma unroll
    for (int nf = 0; nf < 2; ++nf) {
      const f32x16 v = acc[mf][nf];
      const int cc = colb + nf * 32;
#pragma unroll
      for (int reg = 0; reg < 16; ++reg) {
        const int rr = rowb + mf * 32 + (reg & 3) + 8 * (reg >> 2);
        const float val = v[reg];
        if constexpr (MODE == 1) {
          Cb[(long)rr * ldc + cc] = (bf16_t)(val + aux0[rr]);
        } else if constexpr (MODE == 3) {
          Cb[(long)rr * ldc + cc] = (bf16_t)val;
        } else {
          Cb[(long)rr * ldc + cc] = (bf16_t)fmaxf(val + aux0[cc], 0.0f);
        }
      }
    }
#undef ASH
#undef BSH
}

// ---------------------------------------------------------------------------
// Thin-N kernel for KQ (unchanged from R9).
// ---------------------------------------------------------------------------
__global__ __launch_bounds__(256) void kq_thin(
    const bf16_t* __restrict__ A, const bf16_t* __restrict__ B,
    bf16_t* __restrict__ C,
    const float* __restrict__ bk, const float* __restrict__ bq) {
  const int m0 = blockIdx.x * 64;

  __shared__ bf16_t SM[12288];
#define ASH(b) (&SM[(b) << 11])
#define BSH(b) (&SM[4096 + ((b) << 12)])

  const int tid = threadIdx.x;
  const int w = tid >> 6, l = tid & 63;
  const int lr = l & 15, lh = l >> 4;

  const int sRow = tid >> 2;
  const int sSl = (tid & 3) ^ ((tid >> 3) & 3);
  const bf16_t* Asrc = A + (long)(m0 + sRow) * 1024 + sSl * 8;
  const bf16_t* Bsrc0 = B + (long)sRow * 1024 + sSl * 8;
  const bf16_t* Bsrc1 = B + (long)(64 + sRow) * 1024 + sSl * 8;

  const int sw = (lh ^ ((lr >> 1) & 3)) * 8;
  const int aOff = (w * 16 + lr) * 32 + sw;

  f32x4 acc[8] = {};

  auto stage = [&](int buf, int k0) {
    gll16(Asrc + k0, ASH(buf) + tid * 8);
    gll16(Bsrc0 + k0, BSH(buf) + tid * 8);
    gll16(Bsrc1 + k0, BSH(buf) + 2048 + tid * 8);
  };

  stage(0, 0);
  __syncthreads();
  int cur = 0;

  for (int k0 = 0; k0 < 1024; k0 += 32) {
    if (k0 + 32 < 1024) stage(cur ^ 1, k0 + 32);

    const bf16x8_t aF = *(const bf16x8_t*)(ASH(cur) + aOff);
    bf16x8_t bF[8];
#pragma unroll
    for (int j = 0; j < 8; ++j)
      bF[j] = *(const bf16x8_t*)(BSH(cur) + (j * 16 + lr) * 32 + sw);
#pragma unroll
    for (int j = 0; j < 8; ++j)
      acc[j] = __builtin_amdgcn_mfma_f32_16x16x32_bf16(aF, bF[j], acc[j], 0, 0, 0);

    __syncthreads();
    cur ^= 1;
  }

  {
#pragma unroll
    for (int j = 0; j < 8; ++j) {
      const f32x4 v = acc[j];
      const int cl = j * 16 + lr;
      const float b = (cl < 64) ? bk[cl] : bq[cl - 64];
      const float s = (cl < 64) ? 0.125f : 1.0f;
#pragma unroll
      for (int r = 0; r < 4; ++r) {
        const int rl = w * 16 + lh * 4 + r;
        SM[rl * 128 + (cl ^ (lh << 4))] = (bf16_t)((v[r] + b) * s);
      }
    }
    __syncthreads();
    const int chunk = tid & 15, rsub = tid >> 4;
#pragma unroll
    for (int pp = 0; pp < 4; ++pp) {
      const int rl = pp * 16 + rsub;
      const int sc = chunk ^ (((rl >> 2) & 3) << 1);
      const bf16x8_t vv = *(const bf16x8_t*)&SM[rl * 128 + sc * 8];
      *(bf16x8_t*)&C[(long)(m0 + rl) * 128 + chunk * 8] = vv;
    }
  }
#undef ASH
#undef BSH
}

// ---------------------------------------------------------------------------
// 128x128 2-phase kernel (scores) with coalesced LDS-bounce epilogue.
// ---------------------------------------------------------------------------
template <int MODE, int MFAST>
__global__ __launch_bounds__(256) void gemm_bt(
    const bf16_t* __restrict__ A, const bf16_t* __restrict__ B,
    void* __restrict__ Cv, int M, int N, int K, int lda, int ldb, int ldc,
    long sAb, long sBb, long sCb,
    const float* __restrict__ aux0, const float* __restrict__ aux1, long sAux) {
  const int gx = gridDim.x, gy = gridDim.y;
  const int gxy = gx * gy;
  const int nwg = gxy * (int)gridDim.z;
  const int orig = blockIdx.x + gx * blockIdx.y + gxy * blockIdx.z;
  const int q = nwg >> 3, r8 = nwg & 7;
  const int xcd = orig & 7, seq = orig >> 3;
  const int lid = (xcd < r8 ? xcd * (q + 1) : r8 * (q + 1) + (xcd - r8) * q) + seq;
  const int bz = lid / gxy;
  const int rem = lid - bz * gxy;
  const int bx = MFAST ? (rem / gy) : (rem % gx);
  const int by = MFAST ? (rem % gy) : (rem / gx);

  A += (long)bz * sAb;
  B += (long)bz * sBb;
  const float* a0 = aux0 + (long)bz * sAux;

  const int m0 = by * 128;
  const int n0 = bx * 128;

  __shared__ bf16_t SM[16384];
#define ASH(b) (&SM[(b) << 12])
#define BSH(b) (&SM[8192 + ((b) << 12)])

  const int tid = threadIdx.x;
  const int w = tid >> 6, l = tid & 63;
  const int wr = w >> 1, wc = w & 1;
  const int lr = l & 15, lh = l >> 4;

  const int srow = l >> 2;
  const int scol = (((l & 3) ^ (srow & 3)) << 3);

  f32x4 acc[4][4] = {};

  auto stage = [&](int buf, int k0) {
#pragma unroll
    for (int half = 0; half < 2; ++half) {
      const int i = 2 * w + half;
      const int row = (i << 4) + srow;
      gll16(A + (long)(m0 + row) * lda + k0 + scol, ASH(buf) + (i << 9));
      gll16(B + (long)(n0 + row) * ldb + k0 + scol, BSH(buf) + (i << 9));
    }
  };

  stage(0, 0);
  __syncthreads();
  int cur = 0;
  const int sw = ((lh ^ (lr & 3)) << 3);

  for (int k0 = 0; k0 < K; k0 += 32) {
    if (k0 + 32 < K) stage(cur ^ 1, k0 + 32);

    bf16x8_t af[4], bfm[4];
#pragma unroll
    for (int m = 0; m < 4; ++m)
      af[m] = *(const bf16x8_t*)(ASH(cur) + (((wr << 6) + (m << 4) + lr) << 5) + sw);
#pragma unroll
    for (int n = 0; n < 4; ++n)
      bfm[n] = *(const bf16x8_t*)(BSH(cur) + (((wc << 6) + (n << 4) + lr) << 5) + sw);
#pragma unroll
    for (int m = 0; m < 4; ++m)
#pragma unroll
      for (int n = 0; n < 4; ++n)
        acc[m][n] = __builtin_amdgcn_mfma_f32_16x16x32_bf16(af[m], bfm[n], acc[m][n], 0, 0, 0);

    __syncthreads();
    cur ^= 1;
  }

  {
    const int rowb = (wr << 6) + (lh << 2);
    const int colb = (wc << 6) + lr;
#pragma unroll
    for (int m = 0; m < 4; ++m)
#pragma unroll
      for (int n = 0; n < 4; ++n) {
        const f32x4 v = acc[m][n];
        const int cl = colb + (n << 4);
#pragma unroll
        for (int r = 0; r < 4; ++r) {
          const int rl = rowb + (m << 4) + r;
          const float zz = v[r] + a0[m0 + rl];
          SM[rl * 128 + (cl ^ (lh << 4))] =
              (bf16_t)__builtin_amdgcn_rcpf(1.0f + __expf(-zz));
        }
      }
    __syncthreads();
    bf16_t* Cb = (bf16_t*)Cv + (long)bz * sCb;
    const int chunk = tid & 15, rsub = tid >> 4;
#pragma unroll
    for (int pp = 0; pp < 8; ++pp) {
      const int rl = pp * 16 + rsub;
      const int sc = chunk ^ (((rl >> 2) & 3) << 1);
      const bf16x8_t vv = *(const bf16x8_t*)&SM[rl * 128 + sc * 8];
      *(bf16x8_t*)&Cb[(long)(m0 + rl) * ldc + n0 + chunk * 8] = vv;
    }
  }
#undef ASH
#undef BSH
}

// ---------------------------------------------------------------------------
__global__ __launch_bounds__(256) void cast_bias_kernel(
    const float* __restrict__ x, const float* __restrict__ Wb,
    const float* __restrict__ bb, bf16_t* __restrict__ x_bf,
    float* __restrict__ biases) {
  const int r = blockIdx.x * 4 + (threadIdx.x >> 6);
  const int l = threadIdx.x & 63;
  const float* xr = x + (long)r * 1024;
  bf16_t* orow = x_bf + (long)r * 1024;
  float s = 0.f;
#pragma unroll
  for (int i = 0; i < 4; ++i) {
    const int off = l * 4 + i * 256;
    const float4 v = *(const float4*)(xr + off);
    const float4 w = *(const float4*)(Wb + off);
    s += v.x * w.x + v.y * w.y + v.z * w.z + v.w * w.w;
    bf16x4_t o;
    o[0] = (bf16_t)v.x; o[1] = (bf16_t)v.y; o[2] = (bf16_t)v.z; o[3] = (bf16_t)v.w;
    *(bf16x4_t*)(orow + off) = o;
  }
#pragma unroll
  for (int off = 1; off < 64; off <<= 1) s += __shfl_xor(s, off);
  if (l == 0) biases[r] = s + bb[0];
}

__global__ __launch_bounds__(256) void transpose_cast_kernel(
    const float* __restrict__ in, bf16_t* __restrict__ out, int R, int C) {
  __shared__ float t[32][33];
  const int c0 = blockIdx.x * 32, r0 = blockIdx.y * 32;
  const int tx = threadIdx.x & 31, ty = threadIdx.x >> 5;
#pragma unroll
  for (int i = 0; i < 4; ++i) {
    const int rl = ty * 4 + i;
    t[rl][tx] = in[(long)(r0 + rl) * C + c0 + tx];
  }
  __syncthreads();
#pragma unroll
  for (int i = 0; i < 4; ++i) {
    const int rl = ty * 4 + i;
    out[(long)(c0 + rl) * R + r0 + tx] = (bf16_t)t[tx][rl];
  }
}

// wave-per-row LayerNorm (no block barriers): res = bf16(LN(x+attn)*g+be)
__global__ __launch_bounds__(256) void ln1_kernel(
    const bf16_t* __restrict__ x, const bf16_t* __restrict__ attn,
    const float* __restrict__ g, const float* __restrict__ be,
    bf16_t* __restrict__ res) {
  const int w = threadIdx.x >> 6, l = threadIdx.x & 63;
  const long r = (long)blockIdx.x * 4 + w;
  const bf16_t* xr = x + r * 1024;
  const bf16_t* ar = attn + r * 1024;
  float y[16];
  float s = 0.f, ss = 0.f;
#pragma unroll
  for (int h = 0; h < 2; ++h) {
    const int base = h * 512 + l * 8;
    const bf16x8_t xv = *(const bf16x8_t*)(xr + base);
    const bf16x8_t av = *(const bf16x8_t*)(ar + base);
#pragma unroll
    for (int j = 0; j < 8; ++j) {
      const float yy = (float)xv[j] + (float)av[j];
      y[h * 8 + j] = yy;
      s += yy; ss += yy * yy;
    }
  }
#pragma unroll
  for (int off = 1; off < 64; off <<= 1) {
    s += __shfl_xor(s, off);
    ss += __shfl_xor(ss, off);
  }
  const float mean = s * (1.0f / 1024.0f);
  const float rs = rsqrtf(ss * (1.0f / 1024.0f) - mean * mean + 1e-5f);
  bf16_t* orow = res + r * 1024;
#pragma unroll
  for (int h = 0; h < 2; ++h) {
    const int base = h * 512 + l * 8;
    bf16x8_t o;
#pragma unroll
    for (int j = 0; j < 8; ++j)
      o[j] = (bf16_t)((y[h * 8 + j] - mean) * rs * g[base + j] + be[base + j]);
    *(bf16x8_t*)(orow + base) = o;
  }
}

// wave-per-row: out = LN(res + h), fp32 out
__global__ __launch_bounds__(256) void ln2_kernel(
    const bf16_t* __restrict__ res, const bf16_t* __restrict__ hh,
    float* __restrict__ out) {
  const int w = threadIdx.x >> 6, l = threadIdx.x & 63;
  const long r = (long)blockIdx.x * 4 + w;
  const bf16_t* rr = res + r * 1024;
  const bf16_t* hr = hh + r * 1024;
  float y[16];
  float s = 0.f, ss = 0.f;
#pragma unroll
  for (int h = 0; h < 2; ++h) {
    const int base = h * 512 + l * 8;
    const bf16x8_t rv = *(const bf16x8_t*)(rr + base);
    const bf16x8_t hv = *(const bf16x8_t*)(hr + base);
#pragma unroll
    for (int j = 0; j < 8; ++j) {
      const float yy = (float)rv[j] + (float)hv[j];
      y[h * 8 + j] = yy;
      s += yy; ss += yy * yy;
    }
  }
#pragma unroll
  for (int off = 1; off < 64; off <<= 1) {
    s += __shfl_xor(s, off);
    ss += __shfl_xor(ss, off);
  }
  const float mean = s * (1.0f / 1024.0f);
  const float rs = rsqrtf(ss * (1.0f / 1024.0f) - mean * mean + 1e-5f);
  float* orow = out + r * 1024;
#pragma unroll
  for (int h = 0; h < 2; ++h) {
    const int base = h * 512 + l * 8;
    float4 o1, o2;
    o1.x = (y[h * 8 + 0] - mean) * rs; o1.y = (y[h * 8 + 1] - mean) * rs;
    o1.z = (y[h * 8 + 2] - mean) * rs; o1.w = (y[h * 8 + 3] - mean) * rs;
    o2.x = (y[h * 8 + 4] - mean) * rs; o2.y = (y[h * 8 + 5] - mean) * rs;
    o2.z = (y[h * 8 + 6] - mean) * rs; o2.w = (y[h * 8 + 7] - mean) * rs;
    *(float4*)(orow + base) = o1;
    *(float4*)(orow + base + 4) = o2;
  }
}

// ---------------------------------------------------------------------------
extern "C" void kernel_launch(void* const* d_in, const int* in_sizes, int n_in,
                              void* d_out, int out_size, void* d_ws, size_t ws_size,
                              hipStream_t stream) {
  const float* x   = (const float*)d_in[0];
  const float* Wk  = (const float*)d_in[1];
  const float* bk  = (const float*)d_in[2];
  const float* Wq  = (const float*)d_in[3];
  const float* bq  = (const float*)d_in[4];
  const float* Wv  = (const float*)d_in[5];
  const float* bv  = (const float*)d_in[6];
  const float* Wb  = (const float*)d_in[7];
  const float* bb  = (const float*)d_in[8];
  const float* W1  = (const float*)d_in[9];
  const float* b1  = (const float*)d_in[10];
  const float* g1  = (const float*)d_in[11];
  const float* be1 = (const float*)d_in[12];
  float* out = (float*)d_out;

  char* ws = (char*)d_ws;
  bf16_t* x_bf    = (bf16_t*)(ws + 0);           //  32 MB  [16384][1024]
  bf16_t* vt_bf   = (bf16_t*)(ws + 33554432);    //  32 MB  V^T [1024][16384]
  bf16_t* kq_bf   = (bf16_t*)(ws + 67108864);    //   4 MB  [16384][128]
  bf16_t* Wkqt    = (bf16_t*)(ws + 71303168);    // 256 KB  [128][1024]
  bf16_t* Wvt     = (bf16_t*)(ws + 71565312);    //   2 MB
  bf16_t* W1t     = (bf16_t*)(ws + 73662464);    //   2 MB
  float*  biases  = (float*) (ws + 75759616);    //  64 KB
  bf16_t* scores  = (bf16_t*)(ws + 75825152);    //  64 MB  [8][2048][2048]
  bf16_t* attn_bf = (bf16_t*)(ws + 142934016);   //  32 MB  [8][2048][1024]
  bf16_t* res_bf  = (bf16_t*)(ws + 176488448);   //  32 MB
  bf16_t* h_bf    = attn_bf;                     // alias: attn dead after ln1

  cast_bias_kernel<<<4096, 256, 0, stream>>>(x, Wb, bb, x_bf, biases);
  transpose_cast_kernel<<<dim3(2, 32), 256, 0, stream>>>(Wk, Wkqt, 1024, 64);
  transpose_cast_kernel<<<dim3(2, 32), 256, 0, stream>>>(Wq, Wkqt + 64 * 1024, 1024, 64);
  transpose_cast_kernel<<<dim3(32, 32), 256, 0, stream>>>(Wv, Wvt, 1024, 1024);
  transpose_cast_kernel<<<dim3(32, 32), 256, 0, stream>>>(W1, W1t, 1024, 1024);

  // keys|queries: [16384][128], thin-N kernel, 256 blocks
  kq_thin<<<256, 256, 0, stream>>>(x_bf, Wkqt, kq_bf, bk, bq);

  // V^T = Wv^T @ x^T (+bv row bias): M=1024, N=16384, K=1024; MFAST
  gemm256<1, 1><<<dim3(64, 4, 1), 512, 0, stream>>>(
      Wvt, x_bf, vt_bf, 1024, 1024, 1024, 16384, 0, 0, 0, bv);

  // scores = sigmoid(keys.queries^T + bias_i), batched (K=64 -> 128x128 kernel)
  gemm_bt<2, 0><<<dim3(16, 16, 8), 256, 0, stream>>>(
      kq_bf, kq_bf + 64, scores, 2048, 2048, 64, 128, 128, 2048,
      2048L * 128, 2048L * 128, 2048L * 2048, biases, nullptr, 2048);

  // attn = scores @ V: M=2048, N=1024, K=2048, batch 8
  gemm256<3, 0><<<dim3(4, 8, 8), 512, 0, stream>>>(
      scores, vt_bf, attn_bf, 2048, 2048, 16384, 1024,
      2048L * 2048, 2048, 2048L * 1024, nullptr);

  // res = bf16(LN(x+attn)*g1+be1)
  ln1_kernel<<<4096, 256, 0, stream>>>(x_bf, attn_bf, g1, be1, res_bf);

  // h = relu(res @ W1 + b1): M=16384, N=1024, K=1024
  gemm256<4, 0><<<dim3(4, 64, 1), 512, 0, stream>>>(
      res_bf, W1t, h_bf, 1024, 1024, 1024, 1024, 0, 0, 0, b1);

  // out = LN(res + h)
  ln2_kernel<<<4096, 256, 0, stream>>>(res_bf, h_bf, out);
}

// Round 12
// 240.872 us; speedup vs baseline: 1.0238x; 1.0238x over previous
//
#include <hip/hip_runtime.h>
#include <math.h>

// ---------------------------------------------------------------------------
// AttentionEncoder: B=8, S=2048, D=1024, K=64
// Round 12: gemm256p race FIXED — R11's pipeline never committed A1/B1 of the
// next tile (single vmcnt(4) covers A0/B0 only) -> intermittent failure.
// Now: second sync at ph1 {vmcnt(2) (vmcnt(0) on last tile) + barrier} commits
// A1,B1 before their reads. 2 barriers/K-tile + depth-1 register pipelining.
// VT/FF remain on the R9 control kernel (in-run A/B).
// ---------------------------------------------------------------------------

typedef __bf16 bf16_t;
typedef __bf16 bf16x4_t __attribute__((ext_vector_type(4)));
typedef __bf16 bf16x8_t __attribute__((ext_vector_type(8)));
typedef float  f32x4    __attribute__((ext_vector_type(4)));

#define DEV static __device__ __forceinline__

DEV void gll16(const void* g, void* l) {
  __builtin_amdgcn_global_load_lds(
      (const __attribute__((address_space(1))) void*)g,
      (__attribute__((address_space(3))) void*)l, 16, 0, 0);
}

// ---------------------------------------------------------------------------
// R9 gemm256 (control): 4 phases/K-tile, pre-barrier reads, vmcnt(4) P2/P4.
// MODE: 1 VT (bf16, +bv[row]) ; 4 FF (bf16, relu(+b1[col]))
// ---------------------------------------------------------------------------
template <int MODE, int MFAST>
__global__ __launch_bounds__(512, 2) void gemm256(
    const bf16_t* __restrict__ A, const bf16_t* __restrict__ B,
    bf16_t* __restrict__ C, int K, int lda, int ldb, int ldc,
    long sAb, long sBb, long sCb, const float* __restrict__ aux0) {
  const int gx = gridDim.x, gy = gridDim.y;
  const int gxy = gx * gy;
  const int nwg = gxy * (int)gridDim.z;
  const int orig = blockIdx.x + gx * blockIdx.y + gxy * blockIdx.z;
  const int lid = (orig & 7) * (nwg >> 3) + (orig >> 3);
  const int bz = lid / gxy;
  const int rem = lid - bz * gxy;
  const int bx = MFAST ? (rem / gy) : (rem % gx);
  const int by = MFAST ? (rem % gy) : (rem / gx);

  A += (long)bz * sAb;
  B += (long)bz * sBb;
  const int m0 = by * 256, n0 = bx * 256;

  __shared__ bf16_t SM[65536];
#define ASH(b, h) (&SM[(((b)*2 + (h)) << 13)])
#define BSH(b, h) (&SM[32768 + (((b)*2 + (h)) << 13)])

  const int tid = threadIdx.x;
  const int wid = tid >> 6, l = tid & 63;
  const int wr = wid >> 2, wc = wid & 3;
  const int lr = l & 15, lh = l >> 4;

  const int sRow = tid >> 2;
  const int sSl = (tid & 3) ^ ((tid >> 3) & 3);
  const bf16_t* Asrc = A + (long)(m0 + sRow) * lda + sSl * 8;
  const bf16_t* Bsrc = B + (long)(n0 + sRow) * ldb + sSl * 8;
  const long aStep = (long)128 * lda, bStep = (long)128 * ldb;

#define STAGE_A(b, h, kt) do { \
    const bf16_t* s_ = Asrc + (kt) * 64 + (h) * 32; \
    gll16(s_,         ASH(b, h) + tid * 8); \
    gll16(s_ + aStep, ASH(b, h) + 4096 + tid * 8); } while (0)
#define STAGE_B(b, h, kt) do { \
    const bf16_t* s_ = Bsrc + (kt) * 64 + (h) * 32; \
    gll16(s_,         BSH(b, h) + tid * 8); \
    gll16(s_ + bStep, BSH(b, h) + 4096 + tid * 8); } while (0)

  const int sw = (lh ^ ((lr >> 1) & 3)) * 8;
  const int aOff = (wr * 128 + lr) * 32 + sw;
  const int bOff = (wc * 64 + lr) * 32 + sw;

  f32x4 acc[8][4] = {};
  const int NT = K >> 6;

  STAGE_A(0, 0, 0); STAGE_B(0, 0, 0); STAGE_A(0, 1, 0); STAGE_B(0, 1, 0);
  asm volatile("s_waitcnt vmcnt(4)" ::: "memory");
  __builtin_amdgcn_s_barrier();

#define PHASE_SYNC() do { \
    __builtin_amdgcn_sched_barrier(0); \
    __builtin_amdgcn_s_barrier(); \
    asm volatile("s_waitcnt lgkmcnt(0)" ::: "memory"); \
    __builtin_amdgcn_sched_barrier(0); } while (0)
#define MFMA_LO() do { \
    __builtin_amdgcn_s_setprio(1); \
    _Pragma("unroll") for (int m = 0; m < 4; ++m) \
    _Pragma("unroll") for (int n = 0; n < 4; ++n) \
      acc[m][n] = __builtin_amdgcn_mfma_f32_16x16x32_bf16(aF[m], bF[n], acc[m][n], 0, 0, 0); \
    __builtin_amdgcn_s_setprio(0); } while (0)
#define MFMA_HI() do { \
    __builtin_amdgcn_s_setprio(1); \
    _Pragma("unroll") for (int m = 0; m < 4; ++m) \
    _Pragma("unroll") for (int n = 0; n < 4; ++n) \
      acc[m + 4][n] = __builtin_amdgcn_mfma_f32_16x16x32_bf16(aG[m], bF[n], acc[m + 4][n], 0, 0, 0); \
    __builtin_amdgcn_s_setprio(0); } while (0)

  for (int t = 0; t < NT; ++t) {
    const int p = t & 1, q = p ^ 1;
    const bool pf = (t + 1 < NT);
    bf16x8_t bF[4], aF[4], aG[4];

#pragma unroll
    for (int n = 0; n < 4; ++n) bF[n] = *(const bf16x8_t*)(BSH(p, 0) + bOff + n * 512);
#pragma unroll
    for (int m = 0; m < 4; ++m) aF[m] = *(const bf16x8_t*)(ASH(p, 0) + aOff + m * 512);
    if (pf) STAGE_A(q, 0, t + 1);
    PHASE_SYNC();
    MFMA_LO();

#pragma unroll
    for (int m = 0; m < 4; ++m) aG[m] = *(const bf16x8_t*)(ASH(p, 0) + aOff + (m + 4) * 512);
    if (pf) {
      STAGE_B(q, 0, t + 1);
      asm volatile("s_waitcnt vmcnt(4)" ::: "memory");
    } else {
      asm volatile("s_waitcnt vmcnt(0)" ::: "memory");
    }
    PHASE_SYNC();
    MFMA_HI();

#pragma unroll
    for (int n = 0; n < 4; ++n) bF[n] = *(const bf16x8_t*)(BSH(p, 1) + bOff + n * 512);
#pragma unroll
    for (int m = 0; m < 4; ++m) aF[m] = *(const bf16x8_t*)(ASH(p, 1) + aOff + m * 512);
    if (pf) STAGE_A(q, 1, t + 1);
    PHASE_SYNC();
    MFMA_LO();

#pragma unroll
    for (int m = 0; m < 4; ++m) aG[m] = *(const bf16x8_t*)(ASH(p, 1) + aOff + (m + 4) * 512);
    if (pf) STAGE_B(q, 1, t + 1);
    asm volatile("s_waitcnt vmcnt(4)" ::: "memory");
    PHASE_SYNC();
    MFMA_HI();
  }
#undef STAGE_A
#undef STAGE_B
#undef PHASE_SYNC
#undef MFMA_LO
#undef MFMA_HI

  bf16_t* Cb = C + (long)bz * sCb;
  const int rowb = m0 + wr * 128 + lh * 4;
  const int colb = n0 + wc * 64 + lr;
#pragma unroll
  for (int m = 0; m < 8; ++m)
#pragma unroll
    for (int n = 0; n < 4; ++n) {
      const f32x4 v = acc[m][n];
      const int cc = colb + n * 16;
#pragma unroll
      for (int r = 0; r < 4; ++r) {
        const int rr = rowb + m * 16 + r;
        const float val = v[r];
        if constexpr (MODE == 1) {
          Cb[(long)rr * ldc + cc] = (bf16_t)(val + aux0[rr]);
        } else {
          Cb[(long)rr * ldc + cc] = (bf16_t)fmaxf(val + aux0[cc], 0.0f);
        }
      }
    }
#undef ASH
#undef BSH
}

// ---------------------------------------------------------------------------
// gemm256p (attn): depth-1 register-pipelined phases, race-fixed.
// Stages during tile t fill buf q: ph0->A0, ph1->B0, ph2->A1, ph3->B1.
// Sync points: ph1 {vmcnt(2) [commits A1(p),B1(p)] + barrier} and
// ph3 {lgkm(0); vmcnt(4) [commits A0(q),B0(q)] + barrier}. Counted lgkm
// drains only the PREVIOUS phase's reads; MFMA runs on regs loaded a phase ago.
// ---------------------------------------------------------------------------
template <int MODE>
__global__ __launch_bounds__(512, 2) void gemm256p(
    const bf16_t* __restrict__ A, const bf16_t* __restrict__ B,
    bf16_t* __restrict__ C, int K, int lda, int ldb, int ldc,
    long sAb, long sBb, long sCb, const float* __restrict__ aux0) {
  const int gx = gridDim.x, gy = gridDim.y;
  const int gxy = gx * gy;
  const int nwg = gxy * (int)gridDim.z;
  const int orig = blockIdx.x + gx * blockIdx.y + gxy * blockIdx.z;
  const int lid = (orig & 7) * (nwg >> 3) + (orig >> 3);
  const int bz = lid / gxy;
  const int rem = lid - bz * gxy;
  const int bx = rem % gx;
  const int by = rem / gx;

  A += (long)bz * sAb;
  B += (long)bz * sBb;
  const int m0 = by * 256, n0 = bx * 256;

  __shared__ bf16_t SM[65536];
#define ASH(b, h) (&SM[(((b)*2 + (h)) << 13)])
#define BSH(b, h) (&SM[32768 + (((b)*2 + (h)) << 13)])

  const int tid = threadIdx.x;
  const int wid = tid >> 6, l = tid & 63;
  const int wr = wid >> 2, wc = wid & 3;
  const int lr = l & 15, lh = l >> 4;

  const int sRow = tid >> 2;
  const int sSl = (tid & 3) ^ ((tid >> 3) & 3);
  const bf16_t* Asrc = A + (long)(m0 + sRow) * lda + sSl * 8;
  const bf16_t* Bsrc = B + (long)(n0 + sRow) * ldb + sSl * 8;
  const long aStep = (long)128 * lda, bStep = (long)128 * ldb;

#define STAGE_A(b, h, kt) do { \
    const bf16_t* s_ = Asrc + (kt) * 64 + (h) * 32; \
    gll16(s_,         ASH(b, h) + tid * 8); \
    gll16(s_ + aStep, ASH(b, h) + 4096 + tid * 8); } while (0)
#define STAGE_B(b, h, kt) do { \
    const bf16_t* s_ = Bsrc + (kt) * 64 + (h) * 32; \
    gll16(s_,         BSH(b, h) + tid * 8); \
    gll16(s_ + bStep, BSH(b, h) + 4096 + tid * 8); } while (0)

  const int sw = (lh ^ ((lr >> 1) & 3)) * 8;
  const int aOff = (wr * 128 + lr) * 32 + sw;
  const int bOff = (wc * 64 + lr) * 32 + sw;

  f32x4 acc[8][4] = {};
  const int NT = K >> 6;

#define LGKM(n) do { \
    asm volatile("s_waitcnt lgkmcnt(" #n ")" ::: "memory"); \
    __builtin_amdgcn_sched_barrier(0); } while (0)
#define MFMA16(AS, BS, mo) do { \
    __builtin_amdgcn_s_setprio(1); \
    _Pragma("unroll") for (int m = 0; m < 4; ++m) \
    _Pragma("unroll") for (int n = 0; n < 4; ++n) \
      acc[m + (mo)][n] = __builtin_amdgcn_mfma_f32_16x16x32_bf16(AS[m], BS[n], acc[m + (mo)][n], 0, 0, 0); \
    __builtin_amdgcn_s_setprio(0); } while (0)

  // prologue: stage tile 0 (A0,B0,A1,B1); commit A0,B0; load ph0 registers
  STAGE_A(0, 0, 0); STAGE_B(0, 0, 0); STAGE_A(0, 1, 0); STAGE_B(0, 1, 0);
  asm volatile("s_waitcnt vmcnt(4)" ::: "memory");
  __builtin_amdgcn_s_barrier();

  bf16x8_t aA[4], aB[4], bA[4], bB[4];
#pragma unroll
  for (int n = 0; n < 4; ++n) bA[n] = *(const bf16x8_t*)(BSH(0, 0) + bOff + n * 512);
#pragma unroll
  for (int m = 0; m < 4; ++m) aA[m] = *(const bf16x8_t*)(ASH(0, 0) + aOff + m * 512);

  for (int t = 0; t < NT; ++t) {
    const int p = t & 1, q = p ^ 1;
    const bool pf = (t + 1 < NT);

    // ---- ph0: read aB <- A[p][k0,hi]; stage A0(q); MFMA(k0,lo)=aA*bA ----
#pragma unroll
    for (int m = 0; m < 4; ++m) aB[m] = *(const bf16x8_t*)(ASH(p, 0) + aOff + (m + 4) * 512);
    if (pf) STAGE_A(q, 0, t + 1);
    LGKM(4);                      // drains ph3(t-1)/prologue reads -> aA,bA ready
    MFMA16(aA, bA, 0);

    // ---- ph1: commit A1(p),B1(p) + barrier; read aA<-A[p][k1,lo], bB<-B[p][k1];
    //      stage B0(q); MFMA(k0,hi)=aB*bA ----
    if (pf) {
      asm volatile("s_waitcnt vmcnt(2)" ::: "memory");  // A1(p),B1(p) landed
    } else {
      asm volatile("s_waitcnt vmcnt(0)" ::: "memory");  // last tile: only 4 out
    }
    __builtin_amdgcn_sched_barrier(0);
    __builtin_amdgcn_s_barrier();
#pragma unroll
    for (int m = 0; m < 4; ++m) aA[m] = *(const bf16x8_t*)(ASH(p, 1) + aOff + m * 512);
#pragma unroll
    for (int n = 0; n < 4; ++n) bB[n] = *(const bf16x8_t*)(BSH(p, 1) + bOff + n * 512);
    if (pf) STAGE_B(q, 0, t + 1);
    LGKM(8);                      // drains ph0's 4 -> aB ready
    MFMA16(aB, bA, 4);

    // ---- ph2: read aB <- A[p][k1,hi]; stage A1(q); MFMA(k1,lo)=aA*bB ----
#pragma unroll
    for (int m = 0; m < 4; ++m) aB[m] = *(const bf16x8_t*)(ASH(p, 1) + aOff + (m + 4) * 512);
    if (pf) STAGE_A(q, 1, t + 1);
    LGKM(4);                      // drains ph1's 8 -> aA,bB ready
    MFMA16(aA, bB, 0);

    // ---- ph3: stage B1(q); drain reads; commit A0(q),B0(q) + barrier;
    //      read next tile's bA,aA; MFMA(k1,hi)=aB*bB ----
    if (pf) STAGE_B(q, 1, t + 1);
    asm volatile("s_waitcnt lgkmcnt(0)" ::: "memory");  // ph2's reads done
    if (pf) {
      asm volatile("s_waitcnt vmcnt(4)" ::: "memory");  // A0(q),B0(q) landed
    }
    __builtin_amdgcn_sched_barrier(0);
    __builtin_amdgcn_s_barrier();
    if (pf) {
#pragma unroll
      for (int n = 0; n < 4; ++n) bA[n] = *(const bf16x8_t*)(BSH(q, 0) + bOff + n * 512);
#pragma unroll
      for (int m = 0; m < 4; ++m) aA[m] = *(const bf16x8_t*)(ASH(q, 0) + aOff + m * 512);
    }
    __builtin_amdgcn_sched_barrier(0);
    MFMA16(aB, bB, 4);
  }
#undef STAGE_A
#undef STAGE_B
#undef LGKM
#undef MFMA16

  bf16_t* Cb = C + (long)bz * sCb;
  const int rowb = m0 + wr * 128 + lh * 4;
  const int colb = n0 + wc * 64 + lr;
#pragma unroll
  for (int m = 0; m < 8; ++m)
#pragma unroll
    for (int n = 0; n < 4; ++n) {
      const f32x4 v = acc[m][n];
      const int cc = colb + n * 16;
#pragma unroll
      for (int r = 0; r < 4; ++r) {
        const int rr = rowb + m * 16 + r;
        Cb[(long)rr * ldc + cc] = (bf16_t)v[r];
      }
    }
#undef ASH
#undef BSH
}

// ---------------------------------------------------------------------------
// Thin-N kernel for KQ (unchanged from R9).
// ---------------------------------------------------------------------------
__global__ __launch_bounds__(256) void kq_thin(
    const bf16_t* __restrict__ A, const bf16_t* __restrict__ B,
    bf16_t* __restrict__ C,
    const float* __restrict__ bk, const float* __restrict__ bq) {
  const int m0 = blockIdx.x * 64;

  __shared__ bf16_t SM[12288];
#define ASH(b) (&SM[(b) << 11])
#define BSH(b) (&SM[4096 + ((b) << 12)])

  const int tid = threadIdx.x;
  const int w = tid >> 6, l = tid & 63;
  const int lr = l & 15, lh = l >> 4;

  const int sRow = tid >> 2;
  const int sSl = (tid & 3) ^ ((tid >> 3) & 3);
  const bf16_t* Asrc = A + (long)(m0 + sRow) * 1024 + sSl * 8;
  const bf16_t* Bsrc0 = B + (long)sRow * 1024 + sSl * 8;
  const bf16_t* Bsrc1 = B + (long)(64 + sRow) * 1024 + sSl * 8;

  const int sw = (lh ^ ((lr >> 1) & 3)) * 8;
  const int aOff = (w * 16 + lr) * 32 + sw;

  f32x4 acc[8] = {};

  auto stage = [&](int buf, int k0) {
    gll16(Asrc + k0, ASH(buf) + tid * 8);
    gll16(Bsrc0 + k0, BSH(buf) + tid * 8);
    gll16(Bsrc1 + k0, BSH(buf) + 2048 + tid * 8);
  };

  stage(0, 0);
  __syncthreads();
  int cur = 0;

  for (int k0 = 0; k0 < 1024; k0 += 32) {
    if (k0 + 32 < 1024) stage(cur ^ 1, k0 + 32);

    const bf16x8_t aF = *(const bf16x8_t*)(ASH(cur) + aOff);
    bf16x8_t bF[8];
#pragma unroll
    for (int j = 0; j < 8; ++j)
      bF[j] = *(const bf16x8_t*)(BSH(cur) + (j * 16 + lr) * 32 + sw);
#pragma unroll
    for (int j = 0; j < 8; ++j)
      acc[j] = __builtin_amdgcn_mfma_f32_16x16x32_bf16(aF, bF[j], acc[j], 0, 0, 0);

    __syncthreads();
    cur ^= 1;
  }

  {
#pragma unroll
    for (int j = 0; j < 8; ++j) {
      const f32x4 v = acc[j];
      const int cl = j * 16 + lr;
      const float b = (cl < 64) ? bk[cl] : bq[cl - 64];
      const float s = (cl < 64) ? 0.125f : 1.0f;
#pragma unroll
      for (int r = 0; r < 4; ++r) {
        const int rl = w * 16 + lh * 4 + r;
        SM[rl * 128 + (cl ^ (lh << 4))] = (bf16_t)((v[r] + b) * s);
      }
    }
    __syncthreads();
    const int chunk = tid & 15, rsub = tid >> 4;
#pragma unroll
    for (int pp = 0; pp < 4; ++pp) {
      const int rl = pp * 16 + rsub;
      const int sc = chunk ^ (((rl >> 2) & 3) << 1);
      const bf16x8_t vv = *(const bf16x8_t*)&SM[rl * 128 + sc * 8];
      *(bf16x8_t*)&C[(long)(m0 + rl) * 128 + chunk * 8] = vv;
    }
  }
#undef ASH
#undef BSH
}

// ---------------------------------------------------------------------------
// 128x128 2-phase kernel (scores) with coalesced LDS-bounce epilogue.
// ---------------------------------------------------------------------------
template <int MODE, int MFAST>
__global__ __launch_bounds__(256) void gemm_bt(
    const bf16_t* __restrict__ A, const bf16_t* __restrict__ B,
    void* __restrict__ Cv, int M, int N, int K, int lda, int ldb, int ldc,
    long sAb, long sBb, long sCb,
    const float* __restrict__ aux0, const float* __restrict__ aux1, long sAux) {
  const int gx = gridDim.x, gy = gridDim.y;
  const int gxy = gx * gy;
  const int nwg = gxy * (int)gridDim.z;
  const int orig = blockIdx.x + gx * blockIdx.y + gxy * blockIdx.z;
  const int q = nwg >> 3, r8 = nwg & 7;
  const int xcd = orig & 7, seq = orig >> 3;
  const int lid = (xcd < r8 ? xcd * (q + 1) : r8 * (q + 1) + (xcd - r8) * q) + seq;
  const int bz = lid / gxy;
  const int rem = lid - bz * gxy;
  const int bx = MFAST ? (rem / gy) : (rem % gx);
  const int by = MFAST ? (rem % gy) : (rem / gx);

  A += (long)bz * sAb;
  B += (long)bz * sBb;
  const float* a0 = aux0 + (long)bz * sAux;

  const int m0 = by * 128;
  const int n0 = bx * 128;

  __shared__ bf16_t SM[16384];
#define ASH(b) (&SM[(b) << 12])
#define BSH(b) (&SM[8192 + ((b) << 12)])

  const int tid = threadIdx.x;
  const int w = tid >> 6, l = tid & 63;
  const int wr = w >> 1, wc = w & 1;
  const int lr = l & 15, lh = l >> 4;

  const int srow = l >> 2;
  const int scol = (((l & 3) ^ (srow & 3)) << 3);

  f32x4 acc[4][4] = {};

  auto stage = [&](int buf, int k0) {
#pragma unroll
    for (int half = 0; half < 2; ++half) {
      const int i = 2 * w + half;
      const int row = (i << 4) + srow;
      gll16(A + (long)(m0 + row) * lda + k0 + scol, ASH(buf) + (i << 9));
      gll16(B + (long)(n0 + row) * ldb + k0 + scol, BSH(buf) + (i << 9));
    }
  };

  stage(0, 0);
  __syncthreads();
  int cur = 0;
  const int sw = ((lh ^ (lr & 3)) << 3);

  for (int k0 = 0; k0 < K; k0 += 32) {
    if (k0 + 32 < K) stage(cur ^ 1, k0 + 32);

    bf16x8_t af[4], bfm[4];
#pragma unroll
    for (int m = 0; m < 4; ++m)
      af[m] = *(const bf16x8_t*)(ASH(cur) + (((wr << 6) + (m << 4) + lr) << 5) + sw);
#pragma unroll
    for (int n = 0; n < 4; ++n)
      bfm[n] = *(const bf16x8_t*)(BSH(cur) + (((wc << 6) + (n << 4) + lr) << 5) + sw);
#pragma unroll
    for (int m = 0; m < 4; ++m)
#pragma unroll
      for (int n = 0; n < 4; ++n)
        acc[m][n] = __builtin_amdgcn_mfma_f32_16x16x32_bf16(af[m], bfm[n], acc[m][n], 0, 0, 0);

    __syncthreads();
    cur ^= 1;
  }

  {
    const int rowb = (wr << 6) + (lh << 2);
    const int colb = (wc << 6) + lr;
#pragma unroll
    for (int m = 0; m < 4; ++m)
#pragma unroll
      for (int n = 0; n < 4; ++n) {
        const f32x4 v = acc[m][n];
        const int cl = colb + (n << 4);
#pragma unroll
        for (int r = 0; r < 4; ++r) {
          const int rl = rowb + (m << 4) + r;
          const float zz = v[r] + a0[m0 + rl];
          SM[rl * 128 + (cl ^ (lh << 4))] =
              (bf16_t)__builtin_amdgcn_rcpf(1.0f + __expf(-zz));
        }
      }
    __syncthreads();
    bf16_t* Cb = (bf16_t*)Cv + (long)bz * sCb;
    const int chunk = tid & 15, rsub = tid >> 4;
#pragma unroll
    for (int pp = 0; pp < 8; ++pp) {
      const int rl = pp * 16 + rsub;
      const int sc = chunk ^ (((rl >> 2) & 3) << 1);
      const bf16x8_t vv = *(const bf16x8_t*)&SM[rl * 128 + sc * 8];
      *(bf16x8_t*)&Cb[(long)(m0 + rl) * ldc + n0 + chunk * 8] = vv;
    }
  }
#undef ASH
#undef BSH
}

// ---------------------------------------------------------------------------
__global__ __launch_bounds__(256) void cast_bias_kernel(
    const float* __restrict__ x, const float* __restrict__ Wb,
    const float* __restrict__ bb, bf16_t* __restrict__ x_bf,
    float* __restrict__ biases) {
  const int r = blockIdx.x * 4 + (threadIdx.x >> 6);
  const int l = threadIdx.x & 63;
  const float* xr = x + (long)r * 1024;
  bf16_t* orow = x_bf + (long)r * 1024;
  float s = 0.f;
#pragma unroll
  for (int i = 0; i < 4; ++i) {
    const int off = l * 4 + i * 256;
    const float4 v = *(const float4*)(xr + off);
    const float4 w = *(const float4*)(Wb + off);
    s += v.x * w.x + v.y * w.y + v.z * w.z + v.w * w.w;
    bf16x4_t o;
    o[0] = (bf16_t)v.x; o[1] = (bf16_t)v.y; o[2] = (bf16_t)v.z; o[3] = (bf16_t)v.w;
    *(bf16x4_t*)(orow + off) = o;
  }
#pragma unroll
  for (int off = 1; off < 64; off <<= 1) s += __shfl_xor(s, off);
  if (l == 0) biases[r] = s + bb[0];
}

__global__ __launch_bounds__(256) void transpose_cast_kernel(
    const float* __restrict__ in, bf16_t* __restrict__ out, int R, int C) {
  __shared__ float t[32][33];
  const int c0 = blockIdx.x * 32, r0 = blockIdx.y * 32;
  const int tx = threadIdx.x & 31, ty = threadIdx.x >> 5;
#pragma unroll
  for (int i = 0; i < 4; ++i) {
    const int rl = ty * 4 + i;
    t[rl][tx] = in[(long)(r0 + rl) * C + c0 + tx];
  }
  __syncthreads();
#pragma unroll
  for (int i = 0; i < 4; ++i) {
    const int rl = ty * 4 + i;
    out[(long)(c0 + rl) * R + r0 + tx] = (bf16_t)t[tx][rl];
  }
}

// wave-per-row LayerNorm: res = bf16(LN(x+attn)*g+be)
__global__ __launch_bounds__(256) void ln1_kernel(
    const bf16_t* __restrict__ x, const bf16_t* __restrict__ attn,
    const float* __restrict__ g, const float* __restrict__ be,
    bf16_t* __restrict__ res) {
  const int w = threadIdx.x >> 6, l = threadIdx.x & 63;
  const long r = (long)blockIdx.x * 4 + w;
  const bf16_t* xr = x + r * 1024;
  const bf16_t* ar = attn + r * 1024;
  float y[16];
  float s = 0.f, ss = 0.f;
#pragma unroll
  for (int h = 0; h < 2; ++h) {
    const int base = h * 512 + l * 8;
    const bf16x8_t xv = *(const bf16x8_t*)(xr + base);
    const bf16x8_t av = *(const bf16x8_t*)(ar + base);
#pragma unroll
    for (int j = 0; j < 8; ++j) {
      const float yy = (float)xv[j] + (float)av[j];
      y[h * 8 + j] = yy;
      s += yy; ss += yy * yy;
    }
  }
#pragma unroll
  for (int off = 1; off < 64; off <<= 1) {
    s += __shfl_xor(s, off);
    ss += __shfl_xor(ss, off);
  }
  const float mean = s * (1.0f / 1024.0f);
  const float rs = rsqrtf(ss * (1.0f / 1024.0f) - mean * mean + 1e-5f);
  bf16_t* orow = res + r * 1024;
#pragma unroll
  for (int h = 0; h < 2; ++h) {
    const int base = h * 512 + l * 8;
    bf16x8_t o;
#pragma unroll
    for (int j = 0; j < 8; ++j)
      o[j] = (bf16_t)((y[h * 8 + j] - mean) * rs * g[base + j] + be[base + j]);
    *(bf16x8_t*)(orow + base) = o;
  }
}

// wave-per-row: out = LN(res + h), fp32 out
__global__ __launch_bounds__(256) void ln2_kernel(
    const bf16_t* __restrict__ res, const bf16_t* __restrict__ hh,
    float* __restrict__ out) {
  const int w = threadIdx.x >> 6, l = threadIdx.x & 63;
  const long r = (long)blockIdx.x * 4 + w;
  const bf16_t* rr = res + r * 1024;
  const bf16_t* hr = hh + r * 1024;
  float y[16];
  float s = 0.f, ss = 0.f;
#pragma unroll
  for (int h = 0; h < 2; ++h) {
    const int base = h * 512 + l * 8;
    const bf16x8_t rv = *(const bf16x8_t*)(rr + base);
    const bf16x8_t hv = *(const bf16x8_t*)(hr + base);
#pragma unroll
    for (int j = 0; j < 8; ++j) {
      const float yy = (float)rv[j] + (float)hv[j];
      y[h * 8 + j] = yy;
      s += yy; ss += yy * yy;
    }
  }
#pragma unroll
  for (int off = 1; off < 64; off <<= 1) {
    s += __shfl_xor(s, off);
    ss += __shfl_xor(ss, off);
  }
  const float mean = s * (1.0f / 1024.0f);
  const float rs = rsqrtf(ss * (1.0f / 1024.0f) - mean * mean + 1e-5f);
  float* orow = out + r * 1024;
#pragma unroll
  for (int h = 0; h < 2; ++h) {
    const int base = h * 512 + l * 8;
    float4 o1, o2;
    o1.x = (y[h * 8 + 0] - mean) * rs; o1.y = (y[h * 8 + 1] - mean) * rs;
    o1.z = (y[h * 8 + 2] - mean) * rs; o1.w = (y[h * 8 + 3] - mean) * rs;
    o2.x = (y[h * 8 + 4] - mean) * rs; o2.y = (y[h * 8 + 5] - mean) * rs;
    o2.z = (y[h * 8 + 6] - mean) * rs; o2.w = (y[h * 8 + 7] - mean) * rs;
    *(float4*)(orow + base) = o1;
    *(float4*)(orow + base + 4) = o2;
  }
}

// ---------------------------------------------------------------------------
extern "C" void kernel_launch(void* const* d_in, const int* in_sizes, int n_in,
                              void* d_out, int out_size, void* d_ws, size_t ws_size,
                              hipStream_t stream) {
  const float* x   = (const float*)d_in[0];
  const float* Wk  = (const float*)d_in[1];
  const float* bk  = (const float*)d_in[2];
  const float* Wq  = (const float*)d_in[3];
  const float* bq  = (const float*)d_in[4];
  const float* Wv  = (const float*)d_in[5];
  const float* bv  = (const float*)d_in[6];
  const float* Wb  = (const float*)d_in[7];
  const float* bb  = (const float*)d_in[8];
  const float* W1  = (const float*)d_in[9];
  const float* b1  = (const float*)d_in[10];
  const float* g1  = (const float*)d_in[11];
  const float* be1 = (const float*)d_in[12];
  float* out = (float*)d_out;

  char* ws = (char*)d_ws;
  bf16_t* x_bf    = (bf16_t*)(ws + 0);           //  32 MB  [16384][1024]
  bf16_t* vt_bf   = (bf16_t*)(ws + 33554432);    //  32 MB  V^T [1024][16384]
  bf16_t* kq_bf   = (bf16_t*)(ws + 67108864);    //   4 MB  [16384][128]
  bf16_t* Wkqt    = (bf16_t*)(ws + 71303168);    // 256 KB  [128][1024]
  bf16_t* Wvt     = (bf16_t*)(ws + 71565312);    //   2 MB
  bf16_t* W1t     = (bf16_t*)(ws + 73662464);    //   2 MB
  float*  biases  = (float*) (ws + 75759616);    //  64 KB
  bf16_t* scores  = (bf16_t*)(ws + 75825152);    //  64 MB  [8][2048][2048]
  bf16_t* attn_bf = (bf16_t*)(ws + 142934016);   //  32 MB  [8][2048][1024]
  bf16_t* res_bf  = (bf16_t*)(ws + 176488448);   //  32 MB
  bf16_t* h_bf    = attn_bf;                     // alias: attn dead after ln1

  cast_bias_kernel<<<4096, 256, 0, stream>>>(x, Wb, bb, x_bf, biases);
  transpose_cast_kernel<<<dim3(2, 32), 256, 0, stream>>>(Wk, Wkqt, 1024, 64);
  transpose_cast_kernel<<<dim3(2, 32), 256, 0, stream>>>(Wq, Wkqt + 64 * 1024, 1024, 64);
  transpose_cast_kernel<<<dim3(32, 32), 256, 0, stream>>>(Wv, Wvt, 1024, 1024);
  transpose_cast_kernel<<<dim3(32, 32), 256, 0, stream>>>(W1, W1t, 1024, 1024);

  // keys|queries: [16384][128], thin-N kernel, 256 blocks
  kq_thin<<<256, 256, 0, stream>>>(x_bf, Wkqt, kq_bf, bk, bq);

  // V^T = Wv^T @ x^T (+bv row bias): control kernel (R9 schedule)
  gemm256<1, 1><<<dim3(64, 4, 1), 512, 0, stream>>>(
      Wvt, x_bf, vt_bf, 1024, 1024, 1024, 16384, 0, 0, 0, bv);

  // scores = sigmoid(keys.queries^T + bias_i), batched
  gemm_bt<2, 0><<<dim3(16, 16, 8), 256, 0, stream>>>(
      kq_bf, kq_bf + 64, scores, 2048, 2048, 64, 128, 128, 2048,
      2048L * 128, 2048L * 128, 2048L * 2048, biases, nullptr, 2048);

  // attn = scores @ V: EXPERIMENT kernel (race-fixed register pipeline)
  gemm256p<3><<<dim3(4, 8, 8), 512, 0, stream>>>(
      scores, vt_bf, attn_bf, 2048, 2048, 16384, 1024,
      2048L * 2048, 2048, 2048L * 1024, nullptr);

  // res = bf16(LN(x+attn)*g1+be1)
  ln1_kernel<<<4096, 256, 0, stream>>>(x_bf, attn_bf, g1, be1, res_bf);

  // h = relu(res @ W1 + b1): control kernel (R9 schedule)
  gemm256<4, 0><<<dim3(4, 64, 1), 512, 0, stream>>>(
      res_bf, W1t, h_bf, 1024, 1024, 1024, 1024, 0, 0, 0, b1);

  // out = LN(res + h)
  ln2_kernel<<<4096, 256, 0, stream>>>(res_bf, h_bf, out);
}

// Round 13
// 237.608 us; speedup vs baseline: 1.0379x; 1.0137x over previous
//
#include <hip/hip_runtime.h>
#include <math.h>

// ---------------------------------------------------------------------------
// AttentionEncoder: B=8, S=2048, D=1024, K=64
// Round 13: (a) all three big GEMMs on gemm256p (best schedule, R12);
// (b) NEW scores128 kernel — single K-pass (K=64), one staging burst,
// 3 barriers total, sigmoid + verified LDS-bounce coalesced epilogue,
// 32KB LDS -> ~4 blocks/CU TLP (replaces the 2-phase gemm_bt machinery).
// ---------------------------------------------------------------------------

typedef __bf16 bf16_t;
typedef __bf16 bf16x4_t __attribute__((ext_vector_type(4)));
typedef __bf16 bf16x8_t __attribute__((ext_vector_type(8)));
typedef float  f32x4    __attribute__((ext_vector_type(4)));

#define DEV static __device__ __forceinline__

DEV void gll16(const void* g, void* l) {
  __builtin_amdgcn_global_load_lds(
      (const __attribute__((address_space(1))) void*)g,
      (__attribute__((address_space(3))) void*)l, 16, 0, 0);
}

// ---------------------------------------------------------------------------
// gemm256p: 256x256 tile, BK=64, 512 threads (8 waves 2Mx4N), dbuf LDS,
// depth-1 register-pipelined phases (R12, race-fixed).
// MODE: 1 VT (bf16, +aux0[row]) ; 3 ATTN (bf16) ; 4 FF (bf16, relu(+aux0[col]))
// ---------------------------------------------------------------------------
template <int MODE, int MFAST>
__global__ __launch_bounds__(512, 2) void gemm256p(
    const bf16_t* __restrict__ A, const bf16_t* __restrict__ B,
    bf16_t* __restrict__ C, int K, int lda, int ldb, int ldc,
    long sAb, long sBb, long sCb, const float* __restrict__ aux0) {
  const int gx = gridDim.x, gy = gridDim.y;
  const int gxy = gx * gy;
  const int nwg = gxy * (int)gridDim.z;
  const int orig = blockIdx.x + gx * blockIdx.y + gxy * blockIdx.z;
  const int lid = (orig & 7) * (nwg >> 3) + (orig >> 3);
  const int bz = lid / gxy;
  const int rem = lid - bz * gxy;
  const int bx = MFAST ? (rem / gy) : (rem % gx);
  const int by = MFAST ? (rem % gy) : (rem / gx);

  A += (long)bz * sAb;
  B += (long)bz * sBb;
  const int m0 = by * 256, n0 = bx * 256;

  __shared__ bf16_t SM[65536];
#define ASH(b, h) (&SM[(((b)*2 + (h)) << 13)])
#define BSH(b, h) (&SM[32768 + (((b)*2 + (h)) << 13)])

  const int tid = threadIdx.x;
  const int wid = tid >> 6, l = tid & 63;
  const int wr = wid >> 2, wc = wid & 3;
  const int lr = l & 15, lh = l >> 4;

  const int sRow = tid >> 2;
  const int sSl = (tid & 3) ^ ((tid >> 3) & 3);
  const bf16_t* Asrc = A + (long)(m0 + sRow) * lda + sSl * 8;
  const bf16_t* Bsrc = B + (long)(n0 + sRow) * ldb + sSl * 8;
  const long aStep = (long)128 * lda, bStep = (long)128 * ldb;

#define STAGE_A(b, h, kt) do { \
    const bf16_t* s_ = Asrc + (kt) * 64 + (h) * 32; \
    gll16(s_,         ASH(b, h) + tid * 8); \
    gll16(s_ + aStep, ASH(b, h) + 4096 + tid * 8); } while (0)
#define STAGE_B(b, h, kt) do { \
    const bf16_t* s_ = Bsrc + (kt) * 64 + (h) * 32; \
    gll16(s_,         BSH(b, h) + tid * 8); \
    gll16(s_ + bStep, BSH(b, h) + 4096 + tid * 8); } while (0)

  const int sw = (lh ^ ((lr >> 1) & 3)) * 8;
  const int aOff = (wr * 128 + lr) * 32 + sw;
  const int bOff = (wc * 64 + lr) * 32 + sw;

  f32x4 acc[8][4] = {};
  const int NT = K >> 6;

#define LGKM(n) do { \
    asm volatile("s_waitcnt lgkmcnt(" #n ")" ::: "memory"); \
    __builtin_amdgcn_sched_barrier(0); } while (0)
#define MFMA16(AS, BS, mo) do { \
    __builtin_amdgcn_s_setprio(1); \
    _Pragma("unroll") for (int m = 0; m < 4; ++m) \
    _Pragma("unroll") for (int n = 0; n < 4; ++n) \
      acc[m + (mo)][n] = __builtin_amdgcn_mfma_f32_16x16x32_bf16(AS[m], BS[n], acc[m + (mo)][n], 0, 0, 0); \
    __builtin_amdgcn_s_setprio(0); } while (0)

  // prologue: stage tile 0 (A0,B0,A1,B1); commit A0,B0; load ph0 registers
  STAGE_A(0, 0, 0); STAGE_B(0, 0, 0); STAGE_A(0, 1, 0); STAGE_B(0, 1, 0);
  asm volatile("s_waitcnt vmcnt(4)" ::: "memory");
  __builtin_amdgcn_s_barrier();

  bf16x8_t aA[4], aB[4], bA[4], bB[4];
#pragma unroll
  for (int n = 0; n < 4; ++n) bA[n] = *(const bf16x8_t*)(BSH(0, 0) + bOff + n * 512);
#pragma unroll
  for (int m = 0; m < 4; ++m) aA[m] = *(const bf16x8_t*)(ASH(0, 0) + aOff + m * 512);

  for (int t = 0; t < NT; ++t) {
    const int p = t & 1, q = p ^ 1;
    const bool pf = (t + 1 < NT);

    // ---- ph0: read aB <- A[p][k0,hi]; stage A0(q); MFMA(k0,lo)=aA*bA ----
#pragma unroll
    for (int m = 0; m < 4; ++m) aB[m] = *(const bf16x8_t*)(ASH(p, 0) + aOff + (m + 4) * 512);
    if (pf) STAGE_A(q, 0, t + 1);
    LGKM(4);
    MFMA16(aA, bA, 0);

    // ---- ph1: commit A1(p),B1(p) + barrier; read aA,bB; stage B0(q) ----
    if (pf) {
      asm volatile("s_waitcnt vmcnt(2)" ::: "memory");
    } else {
      asm volatile("s_waitcnt vmcnt(0)" ::: "memory");
    }
    __builtin_amdgcn_sched_barrier(0);
    __builtin_amdgcn_s_barrier();
#pragma unroll
    for (int m = 0; m < 4; ++m) aA[m] = *(const bf16x8_t*)(ASH(p, 1) + aOff + m * 512);
#pragma unroll
    for (int n = 0; n < 4; ++n) bB[n] = *(const bf16x8_t*)(BSH(p, 1) + bOff + n * 512);
    if (pf) STAGE_B(q, 0, t + 1);
    LGKM(8);
    MFMA16(aB, bA, 4);

    // ---- ph2: read aB <- A[p][k1,hi]; stage A1(q); MFMA(k1,lo)=aA*bB ----
#pragma unroll
    for (int m = 0; m < 4; ++m) aB[m] = *(const bf16x8_t*)(ASH(p, 1) + aOff + (m + 4) * 512);
    if (pf) STAGE_A(q, 1, t + 1);
    LGKM(4);
    MFMA16(aA, bB, 0);

    // ---- ph3: stage B1(q); drain; commit A0(q),B0(q) + barrier; read next ----
    if (pf) STAGE_B(q, 1, t + 1);
    asm volatile("s_waitcnt lgkmcnt(0)" ::: "memory");
    if (pf) {
      asm volatile("s_waitcnt vmcnt(4)" ::: "memory");
    }
    __builtin_amdgcn_sched_barrier(0);
    __builtin_amdgcn_s_barrier();
    if (pf) {
#pragma unroll
      for (int n = 0; n < 4; ++n) bA[n] = *(const bf16x8_t*)(BSH(q, 0) + bOff + n * 512);
#pragma unroll
      for (int m = 0; m < 4; ++m) aA[m] = *(const bf16x8_t*)(ASH(q, 0) + aOff + m * 512);
    }
    __builtin_amdgcn_sched_barrier(0);
    MFMA16(aB, bB, 4);
  }
#undef STAGE_A
#undef STAGE_B
#undef LGKM
#undef MFMA16

  bf16_t* Cb = C + (long)bz * sCb;
  const int rowb = m0 + wr * 128 + lh * 4;
  const int colb = n0 + wc * 64 + lr;
#pragma unroll
  for (int m = 0; m < 8; ++m)
#pragma unroll
    for (int n = 0; n < 4; ++n) {
      const f32x4 v = acc[m][n];
      const int cc = colb + n * 16;
#pragma unroll
      for (int r = 0; r < 4; ++r) {
        const int rr = rowb + m * 16 + r;
        const float val = v[r];
        if constexpr (MODE == 1) {
          Cb[(long)rr * ldc + cc] = (bf16_t)(val + aux0[rr]);
        } else if constexpr (MODE == 3) {
          Cb[(long)rr * ldc + cc] = (bf16_t)val;
        } else {
          Cb[(long)rr * ldc + cc] = (bf16_t)fmaxf(val + aux0[cc], 0.0f);
        }
      }
    }
#undef ASH
#undef BSH
}

// ---------------------------------------------------------------------------
// scores128: scores[b][i][j] = sigmoid(keys[b,i].queries[b,j] + biases[b,i]).
// 128x128 tile, K=64 single pass: one staging burst, 32 MFMA/wave, sigmoid,
// LDS-bounce coalesced write. kq layout: [16384][128], keys cols 0-63 (pre-
// scaled), queries cols 64-127. Grid dim3(16,16,8).
// ---------------------------------------------------------------------------
__global__ __launch_bounds__(256) void scores128(
    const bf16_t* __restrict__ kq, bf16_t* __restrict__ C,
    const float* __restrict__ biases) {
  const int orig = blockIdx.x + 16 * blockIdx.y + 256 * blockIdx.z;
  const int lid = (orig & 7) * 256 + (orig >> 3);   // nwg=2048, bijective
  const int bz = lid >> 8;
  const int rem = lid & 255;
  const int bx = rem & 15, by = rem >> 4;

  const bf16_t* A = kq + (long)bz * 2048 * 128;        // keys
  const bf16_t* B = A + 64;                            // queries
  const float* a0 = biases + (long)bz * 2048;
  const int m0 = by * 128, n0 = bx * 128;

  __shared__ bf16_t SM[16384];   // 32 KB: A halves 0..8K, B halves 8K..16K
#define ASH(h) (&SM[(h) << 12])
#define BSH(h) (&SM[8192 + ((h) << 12)])

  const int tid = threadIdx.x;
  const int w = tid >> 6, l = tid & 63;
  const int wr = w >> 1, wc = w & 1;
  const int lr = l & 15, lh = l >> 4;

  // staging: half h = [128 rows][32 cols]; granule g = round*256+tid;
  // row g>>3 (rounds: +64), phys slot tid&3.. linear dest; source slot
  // pre-swizzled (tid&3)^((tid>>3)&3) [(row>>1)&3 invariant under +64].
  const int sRow = tid >> 2;
  const int sSl = ((tid & 3) ^ ((tid >> 3) & 3)) * 8;
  const bf16_t* As = A + (long)(m0 + sRow) * 128 + sSl;
  const bf16_t* Bs = B + (long)(n0 + sRow) * 128 + sSl;
#pragma unroll
  for (int h = 0; h < 2; ++h) {
    gll16(As + h * 32, ASH(h) + tid * 8);
    gll16(As + h * 32 + 64 * 128, ASH(h) + 2048 + tid * 8);
    gll16(Bs + h * 32, BSH(h) + tid * 8);
    gll16(Bs + h * 32 + 64 * 128, BSH(h) + 2048 + tid * 8);
  }
  asm volatile("s_waitcnt vmcnt(0)" ::: "memory");
  __builtin_amdgcn_s_barrier();

  const int sw = (lh ^ ((lr >> 1) & 3)) * 8;
  const int aOff = (wr * 64 + lr) * 32 + sw;
  const int bOff = (wc * 64 + lr) * 32 + sw;

  f32x4 acc[4][4] = {};
#pragma unroll
  for (int h = 0; h < 2; ++h) {
    bf16x8_t aF[4], bF[4];
#pragma unroll
    for (int m = 0; m < 4; ++m) aF[m] = *(const bf16x8_t*)(ASH(h) + aOff + m * 512);
#pragma unroll
    for (int n = 0; n < 4; ++n) bF[n] = *(const bf16x8_t*)(BSH(h) + bOff + n * 512);
#pragma unroll
    for (int m = 0; m < 4; ++m)
#pragma unroll
      for (int n = 0; n < 4; ++n)
        acc[m][n] = __builtin_amdgcn_mfma_f32_16x16x32_bf16(aF[m], bF[n], acc[m][n], 0, 0, 0);
  }

  // sigmoid -> LDS bounce (verified R8 algebra) -> coalesced bf16x8 stores
  __builtin_amdgcn_s_barrier();   // all waves' frag reads consumed
  {
    const int rowb = (wr << 6) + (lh << 2);
    const int colb = (wc << 6) + lr;
#pragma unroll
    for (int m = 0; m < 4; ++m)
#pragma unroll
      for (int n = 0; n < 4; ++n) {
        const f32x4 v = acc[m][n];
        const int cl = colb + (n << 4);
#pragma unroll
        for (int r = 0; r < 4; ++r) {
          const int rl = rowb + (m << 4) + r;
          const float zz = v[r] + a0[m0 + rl];
          SM[rl * 128 + (cl ^ (lh << 4))] =
              (bf16_t)__builtin_amdgcn_rcpf(1.0f + __expf(-zz));
        }
      }
    __syncthreads();
    bf16_t* Cb = C + (long)bz * 2048 * 2048;
    const int chunk = tid & 15, rsub = tid >> 4;
#pragma unroll
    for (int pp = 0; pp < 8; ++pp) {
      const int rl = pp * 16 + rsub;
      const int sc = chunk ^ (((rl >> 2) & 3) << 1);
      const bf16x8_t vv = *(const bf16x8_t*)&SM[rl * 128 + sc * 8];
      *(bf16x8_t*)&Cb[(long)(m0 + rl) * 2048 + n0 + chunk * 8] = vv;
    }
  }
#undef ASH
#undef BSH
}

// ---------------------------------------------------------------------------
// Thin-N kernel for KQ (unchanged from R9).
// ---------------------------------------------------------------------------
__global__ __launch_bounds__(256) void kq_thin(
    const bf16_t* __restrict__ A, const bf16_t* __restrict__ B,
    bf16_t* __restrict__ C,
    const float* __restrict__ bk, const float* __restrict__ bq) {
  const int m0 = blockIdx.x * 64;

  __shared__ bf16_t SM[12288];
#define ASH(b) (&SM[(b) << 11])
#define BSH(b) (&SM[4096 + ((b) << 12)])

  const int tid = threadIdx.x;
  const int w = tid >> 6, l = tid & 63;
  const int lr = l & 15, lh = l >> 4;

  const int sRow = tid >> 2;
  const int sSl = (tid & 3) ^ ((tid >> 3) & 3);
  const bf16_t* Asrc = A + (long)(m0 + sRow) * 1024 + sSl * 8;
  const bf16_t* Bsrc0 = B + (long)sRow * 1024 + sSl * 8;
  const bf16_t* Bsrc1 = B + (long)(64 + sRow) * 1024 + sSl * 8;

  const int sw = (lh ^ ((lr >> 1) & 3)) * 8;
  const int aOff = (w * 16 + lr) * 32 + sw;

  f32x4 acc[8] = {};

  auto stage = [&](int buf, int k0) {
    gll16(Asrc + k0, ASH(buf) + tid * 8);
    gll16(Bsrc0 + k0, BSH(buf) + tid * 8);
    gll16(Bsrc1 + k0, BSH(buf) + 2048 + tid * 8);
  };

  stage(0, 0);
  __syncthreads();
  int cur = 0;

  for (int k0 = 0; k0 < 1024; k0 += 32) {
    if (k0 + 32 < 1024) stage(cur ^ 1, k0 + 32);

    const bf16x8_t aF = *(const bf16x8_t*)(ASH(cur) + aOff);
    bf16x8_t bF[8];
#pragma unroll
    for (int j = 0; j < 8; ++j)
      bF[j] = *(const bf16x8_t*)(BSH(cur) + (j * 16 + lr) * 32 + sw);
#pragma unroll
    for (int j = 0; j < 8; ++j)
      acc[j] = __builtin_amdgcn_mfma_f32_16x16x32_bf16(aF, bF[j], acc[j], 0, 0, 0);

    __syncthreads();
    cur ^= 1;
  }

  {
#pragma unroll
    for (int j = 0; j < 8; ++j) {
      const f32x4 v = acc[j];
      const int cl = j * 16 + lr;
      const float b = (cl < 64) ? bk[cl] : bq[cl - 64];
      const float s = (cl < 64) ? 0.125f : 1.0f;
#pragma unroll
      for (int r = 0; r < 4; ++r) {
        const int rl = w * 16 + lh * 4 + r;
        SM[rl * 128 + (cl ^ (lh << 4))] = (bf16_t)((v[r] + b) * s);
      }
    }
    __syncthreads();
    const int chunk = tid & 15, rsub = tid >> 4;
#pragma unroll
    for (int pp = 0; pp < 4; ++pp) {
      const int rl = pp * 16 + rsub;
      const int sc = chunk ^ (((rl >> 2) & 3) << 1);
      const bf16x8_t vv = *(const bf16x8_t*)&SM[rl * 128 + sc * 8];
      *(bf16x8_t*)&C[(long)(m0 + rl) * 128 + chunk * 8] = vv;
    }
  }
#undef ASH
#undef BSH
}

// ---------------------------------------------------------------------------
__global__ __launch_bounds__(256) void cast_bias_kernel(
    const float* __restrict__ x, const float* __restrict__ Wb,
    const float* __restrict__ bb, bf16_t* __restrict__ x_bf,
    float* __restrict__ biases) {
  const int r = blockIdx.x * 4 + (threadIdx.x >> 6);
  const int l = threadIdx.x & 63;
  const float* xr = x + (long)r * 1024;
  bf16_t* orow = x_bf + (long)r * 1024;
  float s = 0.f;
#pragma unroll
  for (int i = 0; i < 4; ++i) {
    const int off = l * 4 + i * 256;
    const float4 v = *(const float4*)(xr + off);
    const float4 w = *(const float4*)(Wb + off);
    s += v.x * w.x + v.y * w.y + v.z * w.z + v.w * w.w;
    bf16x4_t o;
    o[0] = (bf16_t)v.x; o[1] = (bf16_t)v.y; o[2] = (bf16_t)v.z; o[3] = (bf16_t)v.w;
    *(bf16x4_t*)(orow + off) = o;
  }
#pragma unroll
  for (int off = 1; off < 64; off <<= 1) s += __shfl_xor(s, off);
  if (l == 0) biases[r] = s + bb[0];
}

__global__ __launch_bounds__(256) void transpose_cast_kernel(
    const float* __restrict__ in, bf16_t* __restrict__ out, int R, int C) {
  __shared__ float t[32][33];
  const int c0 = blockIdx.x * 32, r0 = blockIdx.y * 32;
  const int tx = threadIdx.x & 31, ty = threadIdx.x >> 5;
#pragma unroll
  for (int i = 0; i < 4; ++i) {
    const int rl = ty * 4 + i;
    t[rl][tx] = in[(long)(r0 + rl) * C + c0 + tx];
  }
  __syncthreads();
#pragma unroll
  for (int i = 0; i < 4; ++i) {
    const int rl = ty * 4 + i;
    out[(long)(c0 + rl) * R + r0 + tx] = (bf16_t)t[tx][rl];
  }
}

// wave-per-row LayerNorm: res = bf16(LN(x+attn)*g+be)
__global__ __launch_bounds__(256) void ln1_kernel(
    const bf16_t* __restrict__ x, const bf16_t* __restrict__ attn,
    const float* __restrict__ g, const float* __restrict__ be,
    bf16_t* __restrict__ res) {
  const int w = threadIdx.x >> 6, l = threadIdx.x & 63;
  const long r = (long)blockIdx.x * 4 + w;
  const bf16_t* xr = x + r * 1024;
  const bf16_t* ar = attn + r * 1024;
  float y[16];
  float s = 0.f, ss = 0.f;
#pragma unroll
  for (int h = 0; h < 2; ++h) {
    const int base = h * 512 + l * 8;
    const bf16x8_t xv = *(const bf16x8_t*)(xr + base);
    const bf16x8_t av = *(const bf16x8_t*)(ar + base);
#pragma unroll
    for (int j = 0; j < 8; ++j) {
      const float yy = (float)xv[j] + (float)av[j];
      y[h * 8 + j] = yy;
      s += yy; ss += yy * yy;
    }
  }
#pragma unroll
  for (int off = 1; off < 64; off <<= 1) {
    s += __shfl_xor(s, off);
    ss += __shfl_xor(ss, off);
  }
  const float mean = s * (1.0f / 1024.0f);
  const float rs = rsqrtf(ss * (1.0f / 1024.0f) - mean * mean + 1e-5f);
  bf16_t* orow = res + r * 1024;
#pragma unroll
  for (int h = 0; h < 2; ++h) {
    const int base = h * 512 + l * 8;
    bf16x8_t o;
#pragma unroll
    for (int j = 0; j < 8; ++j)
      o[j] = (bf16_t)((y[h * 8 + j] - mean) * rs * g[base + j] + be[base + j]);
    *(bf16x8_t*)(orow + base) = o;
  }
}

// wave-per-row: out = LN(res + h), fp32 out
__global__ __launch_bounds__(256) void ln2_kernel(
    const bf16_t* __restrict__ res, const bf16_t* __restrict__ hh,
    float* __restrict__ out) {
  const int w = threadIdx.x >> 6, l = threadIdx.x & 63;
  const long r = (long)blockIdx.x * 4 + w;
  const bf16_t* rr = res + r * 1024;
  const bf16_t* hr = hh + r * 1024;
  float y[16];
  float s = 0.f, ss = 0.f;
#pragma unroll
  for (int h = 0; h < 2; ++h) {
    const int base = h * 512 + l * 8;
    const bf16x8_t rv = *(const bf16x8_t*)(rr + base);
    const bf16x8_t hv = *(const bf16x8_t*)(hr + base);
#pragma unroll
    for (int j = 0; j < 8; ++j) {
      const float yy = (float)rv[j] + (float)hv[j];
      y[h * 8 + j] = yy;
      s += yy; ss += yy * yy;
    }
  }
#pragma unroll
  for (int off = 1; off < 64; off <<= 1) {
    s += __shfl_xor(s, off);
    ss += __shfl_xor(ss, off);
  }
  const float mean = s * (1.0f / 1024.0f);
  const float rs = rsqrtf(ss * (1.0f / 1024.0f) - mean * mean + 1e-5f);
  float* orow = out + r * 1024;
#pragma unroll
  for (int h = 0; h < 2; ++h) {
    const int base = h * 512 + l * 8;
    float4 o1, o2;
    o1.x = (y[h * 8 + 0] - mean) * rs; o1.y = (y[h * 8 + 1] - mean) * rs;
    o1.z = (y[h * 8 + 2] - mean) * rs; o1.w = (y[h * 8 + 3] - mean) * rs;
    o2.x = (y[h * 8 + 4] - mean) * rs; o2.y = (y[h * 8 + 5] - mean) * rs;
    o2.z = (y[h * 8 + 6] - mean) * rs; o2.w = (y[h * 8 + 7] - mean) * rs;
    *(float4*)(orow + base) = o1;
    *(float4*)(orow + base + 4) = o2;
  }
}

// ---------------------------------------------------------------------------
extern "C" void kernel_launch(void* const* d_in, const int* in_sizes, int n_in,
                              void* d_out, int out_size, void* d_ws, size_t ws_size,
                              hipStream_t stream) {
  const float* x   = (const float*)d_in[0];
  const float* Wk  = (const float*)d_in[1];
  const float* bk  = (const float*)d_in[2];
  const float* Wq  = (const float*)d_in[3];
  const float* bq  = (const float*)d_in[4];
  const float* Wv  = (const float*)d_in[5];
  const float* bv  = (const float*)d_in[6];
  const float* Wb  = (const float*)d_in[7];
  const float* bb  = (const float*)d_in[8];
  const float* W1  = (const float*)d_in[9];
  const float* b1  = (const float*)d_in[10];
  const float* g1  = (const float*)d_in[11];
  const float* be1 = (const float*)d_in[12];
  float* out = (float*)d_out;

  char* ws = (char*)d_ws;
  bf16_t* x_bf    = (bf16_t*)(ws + 0);           //  32 MB  [16384][1024]
  bf16_t* vt_bf   = (bf16_t*)(ws + 33554432);    //  32 MB  V^T [1024][16384]
  bf16_t* kq_bf   = (bf16_t*)(ws + 67108864);    //   4 MB  [16384][128]
  bf16_t* Wkqt    = (bf16_t*)(ws + 71303168);    // 256 KB  [128][1024]
  bf16_t* Wvt     = (bf16_t*)(ws + 71565312);    //   2 MB
  bf16_t* W1t     = (bf16_t*)(ws + 73662464);    //   2 MB
  float*  biases  = (float*) (ws + 75759616);    //  64 KB
  bf16_t* scores  = (bf16_t*)(ws + 75825152);    //  64 MB  [8][2048][2048]
  bf16_t* attn_bf = (bf16_t*)(ws + 142934016);   //  32 MB  [8][2048][1024]
  bf16_t* res_bf  = (bf16_t*)(ws + 176488448);   //  32 MB
  bf16_t* h_bf    = attn_bf;                     // alias: attn dead after ln1

  cast_bias_kernel<<<4096, 256, 0, stream>>>(x, Wb, bb, x_bf, biases);
  transpose_cast_kernel<<<dim3(2, 32), 256, 0, stream>>>(Wk, Wkqt, 1024, 64);
  transpose_cast_kernel<<<dim3(2, 32), 256, 0, stream>>>(Wq, Wkqt + 64 * 1024, 1024, 64);
  transpose_cast_kernel<<<dim3(32, 32), 256, 0, stream>>>(Wv, Wvt, 1024, 1024);
  transpose_cast_kernel<<<dim3(32, 32), 256, 0, stream>>>(W1, W1t, 1024, 1024);

  // keys|queries: [16384][128], thin-N kernel, 256 blocks
  kq_thin<<<256, 256, 0, stream>>>(x_bf, Wkqt, kq_bf, bk, bq);

  // V^T = Wv^T @ x^T (+bv row bias): M=1024, N=16384, K=1024; MFAST
  gemm256p<1, 1><<<dim3(64, 4, 1), 512, 0, stream>>>(
      Wvt, x_bf, vt_bf, 1024, 1024, 1024, 16384, 0, 0, 0, bv);

  // scores = sigmoid(keys.queries^T + bias_i): dedicated single-pass kernel
  scores128<<<dim3(16, 16, 8), 256, 0, stream>>>(kq_bf, scores, biases);

  // attn = scores @ V: M=2048, N=1024, K=2048, batch 8
  gemm256p<3, 0><<<dim3(4, 8, 8), 512, 0, stream>>>(
      scores, vt_bf, attn_bf, 2048, 2048, 16384, 1024,
      2048L * 2048, 2048, 2048L * 1024, nullptr);

  // res = bf16(LN(x+attn)*g1+be1)
  ln1_kernel<<<4096, 256, 0, stream>>>(x_bf, attn_bf, g1, be1, res_bf);

  // h = relu(res @ W1 + b1): M=16384, N=1024, K=1024
  gemm256p<4, 0><<<dim3(4, 64, 1), 512, 0, stream>>>(
      res_bf, W1t, h_bf, 1024, 1024, 1024, 1024, 0, 0, 0, b1);

  // out = LN(res + h)
  ln2_kernel<<<4096, 256, 0, stream>>>(res_bf, h_bf, out);
}

// Round 14
// 235.453 us; speedup vs baseline: 1.0474x; 1.0092x over previous
//
#include <hip/hip_runtime.h>
#include <math.h>

// ---------------------------------------------------------------------------
// AttentionEncoder: B=8, S=2048, D=1024, K=64
// Round 14: occupancy experiment — FF and VT move to gemm128n (256x128 tile,
// BK=32, 48KB LDS -> 512 blocks -> 2 blocks/CU; cross-block TLP hides
// barrier/vmcnt stalls). attn stays on gemm256p as in-run control.
// Also: 4 transpose launches merged into one batched kernel.
// ---------------------------------------------------------------------------

typedef __bf16 bf16_t;
typedef __bf16 bf16x4_t __attribute__((ext_vector_type(4)));
typedef __bf16 bf16x8_t __attribute__((ext_vector_type(8)));
typedef float  f32x4    __attribute__((ext_vector_type(4)));

#define DEV static __device__ __forceinline__

DEV void gll16(const void* g, void* l) {
  __builtin_amdgcn_global_load_lds(
      (const __attribute__((address_space(1))) void*)g,
      (__attribute__((address_space(3))) void*)l, 16, 0, 0);
}

// ---------------------------------------------------------------------------
// gemm128n: 256x128 tile, BK=32, 512 threads (8 waves as 4Mx2N, wave 64x64),
// 2-slot LDS ring (48KB) -> 2 blocks/CU. One vmcnt(0)+barrier per half-step.
// MODE: 1 VT (bf16, +aux0[row]) ; 4 FF (bf16, relu(+aux0[col]))
// ---------------------------------------------------------------------------
template <int MODE, int MFAST>
__global__ __launch_bounds__(512, 4) void gemm128n(
    const bf16_t* __restrict__ A, const bf16_t* __restrict__ B,
    bf16_t* __restrict__ C, int K, int lda, int ldb, int ldc,
    const float* __restrict__ aux0) {
  const int gx = gridDim.x, gy = gridDim.y;
  const int nwg = gx * gy;
  const int orig = blockIdx.x + gx * blockIdx.y;
  const int lid = (orig & 7) * (nwg >> 3) + (orig >> 3);
  const int bx = MFAST ? (lid / gy) : (lid % gx);
  const int by = MFAST ? (lid % gy) : (lid / gx);
  const int m0 = by * 256, n0 = bx * 128;

  __shared__ bf16_t SM[24576];   // A: 2x[256][32]=32KB, B: 2x[128][32]=16KB
#define ASH(s) (&SM[(s) << 13])
#define BSH(s) (&SM[16384 + ((s) << 12)])

  const int tid = threadIdx.x;
  const int wid = tid >> 6, l = tid & 63;
  const int wr = wid >> 1, wc = wid & 1;   // 4M x 2N
  const int lr = l & 15, lh = l >> 4;

  const int sRow = tid >> 2;
  const int sSl = (tid & 3) ^ ((tid >> 3) & 3);
  const bf16_t* Asrc = A + (long)(m0 + sRow) * lda + sSl * 8;
  const bf16_t* Bsrc = B + (long)(n0 + sRow) * ldb + sSl * 8;
  const long aStep = (long)128 * lda;

  const int sw = (lh ^ ((lr >> 1) & 3)) * 8;
  const int aOff = (wr * 64 + lr) * 32 + sw;
  const int bOff = (wc * 64 + lr) * 32 + sw;

  f32x4 acc[4][4] = {};
  const int NT = K >> 5;

  // prologue: stage h=0 into slot 0
  gll16(Asrc, ASH(0) + tid * 8);
  gll16(Asrc + aStep, ASH(0) + 4096 + tid * 8);
  gll16(Bsrc, BSH(0) + tid * 8);

  for (int h = 0; h < NT; ++h) {
    const int s = h & 1;
    // commit stage(h) (own loads) then publish; also gates slot s^1 reuse
    asm volatile("s_waitcnt vmcnt(0)" ::: "memory");
    __builtin_amdgcn_sched_barrier(0);
    __builtin_amdgcn_s_barrier();
    if (h + 1 < NT) {
      const bf16_t* a_ = Asrc + (h + 1) * 32;
      const bf16_t* b_ = Bsrc + (h + 1) * 32;
      gll16(a_, ASH(s ^ 1) + tid * 8);
      gll16(a_ + aStep, ASH(s ^ 1) + 4096 + tid * 8);
      gll16(b_, BSH(s ^ 1) + tid * 8);
    }
    bf16x8_t aF[4], bF[4];
#pragma unroll
    for (int m = 0; m < 4; ++m) aF[m] = *(const bf16x8_t*)(ASH(s) + aOff + m * 512);
#pragma unroll
    for (int n = 0; n < 4; ++n) bF[n] = *(const bf16x8_t*)(BSH(s) + bOff + n * 512);
    asm volatile("s_waitcnt lgkmcnt(0)" ::: "memory");
    __builtin_amdgcn_sched_barrier(0);
    __builtin_amdgcn_s_setprio(1);
#pragma unroll
    for (int m = 0; m < 4; ++m)
#pragma unroll
      for (int n = 0; n < 4; ++n)
        acc[m][n] = __builtin_amdgcn_mfma_f32_16x16x32_bf16(aF[m], bF[n], acc[m][n], 0, 0, 0);
    __builtin_amdgcn_s_setprio(0);
  }

  // epilogue: C/D frag col=lane&15, row=(lane>>4)*4+r  [verified]
  const int rowb = m0 + wr * 64 + lh * 4;
  const int colb = n0 + wc * 64 + lr;
#pragma unroll
  for (int m = 0; m < 4; ++m)
#pragma unroll
    for (int n = 0; n < 4; ++n) {
      const f32x4 v = acc[m][n];
      const int cc = colb + n * 16;
#pragma unroll
      for (int r = 0; r < 4; ++r) {
        const int rr = rowb + m * 16 + r;
        const float val = v[r];
        if constexpr (MODE == 1) {
          C[(long)rr * ldc + cc] = (bf16_t)(val + aux0[rr]);
        } else {
          C[(long)rr * ldc + cc] = (bf16_t)fmaxf(val + aux0[cc], 0.0f);
        }
      }
    }
#undef ASH
#undef BSH
}

// ---------------------------------------------------------------------------
// gemm256p: 256x256 tile, BK=64, 512 threads (8 waves 2Mx4N), dbuf LDS,
// depth-1 register-pipelined phases (R12, race-fixed). attn control kernel.
// ---------------------------------------------------------------------------
template <int MODE>
__global__ __launch_bounds__(512, 2) void gemm256p(
    const bf16_t* __restrict__ A, const bf16_t* __restrict__ B,
    bf16_t* __restrict__ C, int K, int lda, int ldb, int ldc,
    long sAb, long sBb, long sCb, const float* __restrict__ aux0) {
  const int gx = gridDim.x, gy = gridDim.y;
  const int gxy = gx * gy;
  const int nwg = gxy * (int)gridDim.z;
  const int orig = blockIdx.x + gx * blockIdx.y + gxy * blockIdx.z;
  const int lid = (orig & 7) * (nwg >> 3) + (orig >> 3);
  const int bz = lid / gxy;
  const int rem = lid - bz * gxy;
  const int bx = rem % gx;
  const int by = rem / gx;

  A += (long)bz * sAb;
  B += (long)bz * sBb;
  const int m0 = by * 256, n0 = bx * 256;

  __shared__ bf16_t SM[65536];
#define ASH(b, h) (&SM[(((b)*2 + (h)) << 13)])
#define BSH(b, h) (&SM[32768 + (((b)*2 + (h)) << 13)])

  const int tid = threadIdx.x;
  const int wid = tid >> 6, l = tid & 63;
  const int wr = wid >> 2, wc = wid & 3;
  const int lr = l & 15, lh = l >> 4;

  const int sRow = tid >> 2;
  const int sSl = (tid & 3) ^ ((tid >> 3) & 3);
  const bf16_t* Asrc = A + (long)(m0 + sRow) * lda + sSl * 8;
  const bf16_t* Bsrc = B + (long)(n0 + sRow) * ldb + sSl * 8;
  const long aStep = (long)128 * lda, bStep = (long)128 * ldb;

#define STAGE_A(b, h, kt) do { \
    const bf16_t* s_ = Asrc + (kt) * 64 + (h) * 32; \
    gll16(s_,         ASH(b, h) + tid * 8); \
    gll16(s_ + aStep, ASH(b, h) + 4096 + tid * 8); } while (0)
#define STAGE_B(b, h, kt) do { \
    const bf16_t* s_ = Bsrc + (kt) * 64 + (h) * 32; \
    gll16(s_,         BSH(b, h) + tid * 8); \
    gll16(s_ + bStep, BSH(b, h) + 4096 + tid * 8); } while (0)

  const int sw = (lh ^ ((lr >> 1) & 3)) * 8;
  const int aOff = (wr * 128 + lr) * 32 + sw;
  const int bOff = (wc * 64 + lr) * 32 + sw;

  f32x4 acc[8][4] = {};
  const int NT = K >> 6;

#define LGKM(n) do { \
    asm volatile("s_waitcnt lgkmcnt(" #n ")" ::: "memory"); \
    __builtin_amdgcn_sched_barrier(0); } while (0)
#define MFMA16(AS, BS, mo) do { \
    __builtin_amdgcn_s_setprio(1); \
    _Pragma("unroll") for (int m = 0; m < 4; ++m) \
    _Pragma("unroll") for (int n = 0; n < 4; ++n) \
      acc[m + (mo)][n] = __builtin_amdgcn_mfma_f32_16x16x32_bf16(AS[m], BS[n], acc[m + (mo)][n], 0, 0, 0); \
    __builtin_amdgcn_s_setprio(0); } while (0)

  STAGE_A(0, 0, 0); STAGE_B(0, 0, 0); STAGE_A(0, 1, 0); STAGE_B(0, 1, 0);
  asm volatile("s_waitcnt vmcnt(4)" ::: "memory");
  __builtin_amdgcn_s_barrier();

  bf16x8_t aA[4], aB[4], bA[4], bB[4];
#pragma unroll
  for (int n = 0; n < 4; ++n) bA[n] = *(const bf16x8_t*)(BSH(0, 0) + bOff + n * 512);
#pragma unroll
  for (int m = 0; m < 4; ++m) aA[m] = *(const bf16x8_t*)(ASH(0, 0) + aOff + m * 512);

  for (int t = 0; t < NT; ++t) {
    const int p = t & 1, q = p ^ 1;
    const bool pf = (t + 1 < NT);

#pragma unroll
    for (int m = 0; m < 4; ++m) aB[m] = *(const bf16x8_t*)(ASH(p, 0) + aOff + (m + 4) * 512);
    if (pf) STAGE_A(q, 0, t + 1);
    LGKM(4);
    MFMA16(aA, bA, 0);

    if (pf) {
      asm volatile("s_waitcnt vmcnt(2)" ::: "memory");
    } else {
      asm volatile("s_waitcnt vmcnt(0)" ::: "memory");
    }
    __builtin_amdgcn_sched_barrier(0);
    __builtin_amdgcn_s_barrier();
#pragma unroll
    for (int m = 0; m < 4; ++m) aA[m] = *(const bf16x8_t*)(ASH(p, 1) + aOff + m * 512);
#pragma unroll
    for (int n = 0; n < 4; ++n) bB[n] = *(const bf16x8_t*)(BSH(p, 1) + bOff + n * 512);
    if (pf) STAGE_B(q, 0, t + 1);
    LGKM(8);
    MFMA16(aB, bA, 4);

#pragma unroll
    for (int m = 0; m < 4; ++m) aB[m] = *(const bf16x8_t*)(ASH(p, 1) + aOff + (m + 4) * 512);
    if (pf) STAGE_A(q, 1, t + 1);
    LGKM(4);
    MFMA16(aA, bB, 0);

    if (pf) STAGE_B(q, 1, t + 1);
    asm volatile("s_waitcnt lgkmcnt(0)" ::: "memory");
    if (pf) {
      asm volatile("s_waitcnt vmcnt(4)" ::: "memory");
    }
    __builtin_amdgcn_sched_barrier(0);
    __builtin_amdgcn_s_barrier();
    if (pf) {
#pragma unroll
      for (int n = 0; n < 4; ++n) bA[n] = *(const bf16x8_t*)(BSH(q, 0) + bOff + n * 512);
#pragma unroll
      for (int m = 0; m < 4; ++m) aA[m] = *(const bf16x8_t*)(ASH(q, 0) + aOff + m * 512);
    }
    __builtin_amdgcn_sched_barrier(0);
    MFMA16(aB, bB, 4);
  }
#undef STAGE_A
#undef STAGE_B
#undef LGKM
#undef MFMA16

  bf16_t* Cb = C + (long)bz * sCb;
  const int rowb = m0 + wr * 128 + lh * 4;
  const int colb = n0 + wc * 64 + lr;
#pragma unroll
  for (int m = 0; m < 8; ++m)
#pragma unroll
    for (int n = 0; n < 4; ++n) {
      const f32x4 v = acc[m][n];
      const int cc = colb + n * 16;
#pragma unroll
      for (int r = 0; r < 4; ++r) {
        const int rr = rowb + m * 16 + r;
        Cb[(long)rr * ldc + cc] = (bf16_t)v[r];
      }
    }
#undef ASH
#undef BSH
}

// ---------------------------------------------------------------------------
// scores128 (R13): single K-pass, sigmoid, LDS-bounce coalesced write.
// ---------------------------------------------------------------------------
__global__ __launch_bounds__(256) void scores128(
    const bf16_t* __restrict__ kq, bf16_t* __restrict__ C,
    const float* __restrict__ biases) {
  const int orig = blockIdx.x + 16 * blockIdx.y + 256 * blockIdx.z;
  const int lid = (orig & 7) * 256 + (orig >> 3);
  const int bz = lid >> 8;
  const int rem = lid & 255;
  const int bx = rem & 15, by = rem >> 4;

  const bf16_t* A = kq + (long)bz * 2048 * 128;
  const bf16_t* B = A + 64;
  const float* a0 = biases + (long)bz * 2048;
  const int m0 = by * 128, n0 = bx * 128;

  __shared__ bf16_t SM[16384];
#define ASH(h) (&SM[(h) << 12])
#define BSH(h) (&SM[8192 + ((h) << 12)])

  const int tid = threadIdx.x;
  const int w = tid >> 6, l = tid & 63;
  const int wr = w >> 1, wc = w & 1;
  const int lr = l & 15, lh = l >> 4;

  const int sRow = tid >> 2;
  const int sSl = ((tid & 3) ^ ((tid >> 3) & 3)) * 8;
  const bf16_t* As = A + (long)(m0 + sRow) * 128 + sSl;
  const bf16_t* Bs = B + (long)(n0 + sRow) * 128 + sSl;
#pragma unroll
  for (int h = 0; h < 2; ++h) {
    gll16(As + h * 32, ASH(h) + tid * 8);
    gll16(As + h * 32 + 64 * 128, ASH(h) + 2048 + tid * 8);
    gll16(Bs + h * 32, BSH(h) + tid * 8);
    gll16(Bs + h * 32 + 64 * 128, BSH(h) + 2048 + tid * 8);
  }
  asm volatile("s_waitcnt vmcnt(0)" ::: "memory");
  __builtin_amdgcn_s_barrier();

  const int sw = (lh ^ ((lr >> 1) & 3)) * 8;
  const int aOff = (wr * 64 + lr) * 32 + sw;
  const int bOff = (wc * 64 + lr) * 32 + sw;

  f32x4 acc[4][4] = {};
#pragma unroll
  for (int h = 0; h < 2; ++h) {
    bf16x8_t aF[4], bF[4];
#pragma unroll
    for (int m = 0; m < 4; ++m) aF[m] = *(const bf16x8_t*)(ASH(h) + aOff + m * 512);
#pragma unroll
    for (int n = 0; n < 4; ++n) bF[n] = *(const bf16x8_t*)(BSH(h) + bOff + n * 512);
#pragma unroll
    for (int m = 0; m < 4; ++m)
#pragma unroll
      for (int n = 0; n < 4; ++n)
        acc[m][n] = __builtin_amdgcn_mfma_f32_16x16x32_bf16(aF[m], bF[n], acc[m][n], 0, 0, 0);
  }

  __builtin_amdgcn_s_barrier();
  {
    const int rowb = (wr << 6) + (lh << 2);
    const int colb = (wc << 6) + lr;
#pragma unroll
    for (int m = 0; m < 4; ++m)
#pragma unroll
      for (int n = 0; n < 4; ++n) {
        const f32x4 v = acc[m][n];
        const int cl = colb + (n << 4);
#pragma unroll
        for (int r = 0; r < 4; ++r) {
          const int rl = rowb + (m << 4) + r;
          const float zz = v[r] + a0[m0 + rl];
          SM[rl * 128 + (cl ^ (lh << 4))] =
              (bf16_t)__builtin_amdgcn_rcpf(1.0f + __expf(-zz));
        }
      }
    __syncthreads();
    bf16_t* Cb = C + (long)bz * 2048 * 2048;
    const int chunk = tid & 15, rsub = tid >> 4;
#pragma unroll
    for (int pp = 0; pp < 8; ++pp) {
      const int rl = pp * 16 + rsub;
      const int sc = chunk ^ (((rl >> 2) & 3) << 1);
      const bf16x8_t vv = *(const bf16x8_t*)&SM[rl * 128 + sc * 8];
      *(bf16x8_t*)&Cb[(long)(m0 + rl) * 2048 + n0 + chunk * 8] = vv;
    }
  }
#undef ASH
#undef BSH
}

// ---------------------------------------------------------------------------
// Thin-N kernel for KQ (unchanged from R9).
// ---------------------------------------------------------------------------
__global__ __launch_bounds__(256) void kq_thin(
    const bf16_t* __restrict__ A, const bf16_t* __restrict__ B,
    bf16_t* __restrict__ C,
    const float* __restrict__ bk, const float* __restrict__ bq) {
  const int m0 = blockIdx.x * 64;

  __shared__ bf16_t SM[12288];
#define ASH(b) (&SM[(b) << 11])
#define BSH(b) (&SM[4096 + ((b) << 12)])

  const int tid = threadIdx.x;
  const int w = tid >> 6, l = tid & 63;
  const int lr = l & 15, lh = l >> 4;

  const int sRow = tid >> 2;
  const int sSl = (tid & 3) ^ ((tid >> 3) & 3);
  const bf16_t* Asrc = A + (long)(m0 + sRow) * 1024 + sSl * 8;
  const bf16_t* Bsrc0 = B + (long)sRow * 1024 + sSl * 8;
  const bf16_t* Bsrc1 = B + (long)(64 + sRow) * 1024 + sSl * 8;

  const int sw = (lh ^ ((lr >> 1) & 3)) * 8;
  const int aOff = (w * 16 + lr) * 32 + sw;

  f32x4 acc[8] = {};

  auto stage = [&](int buf, int k0) {
    gll16(Asrc + k0, ASH(buf) + tid * 8);
    gll16(Bsrc0 + k0, BSH(buf) + tid * 8);
    gll16(Bsrc1 + k0, BSH(buf) + 2048 + tid * 8);
  };

  stage(0, 0);
  __syncthreads();
  int cur = 0;

  for (int k0 = 0; k0 < 1024; k0 += 32) {
    if (k0 + 32 < 1024) stage(cur ^ 1, k0 + 32);

    const bf16x8_t aF = *(const bf16x8_t*)(ASH(cur) + aOff);
    bf16x8_t bF[8];
#pragma unroll
    for (int j = 0; j < 8; ++j)
      bF[j] = *(const bf16x8_t*)(BSH(cur) + (j * 16 + lr) * 32 + sw);
#pragma unroll
    for (int j = 0; j < 8; ++j)
      acc[j] = __builtin_amdgcn_mfma_f32_16x16x32_bf16(aF, bF[j], acc[j], 0, 0, 0);

    __syncthreads();
    cur ^= 1;
  }

  {
#pragma unroll
    for (int j = 0; j < 8; ++j) {
      const f32x4 v = acc[j];
      const int cl = j * 16 + lr;
      const float b = (cl < 64) ? bk[cl] : bq[cl - 64];
      const float s = (cl < 64) ? 0.125f : 1.0f;
#pragma unroll
      for (int r = 0; r < 4; ++r) {
        const int rl = w * 16 + lh * 4 + r;
        SM[rl * 128 + (cl ^ (lh << 4))] = (bf16_t)((v[r] + b) * s);
      }
    }
    __syncthreads();
    const int chunk = tid & 15, rsub = tid >> 4;
#pragma unroll
    for (int pp = 0; pp < 4; ++pp) {
      const int rl = pp * 16 + rsub;
      const int sc = chunk ^ (((rl >> 2) & 3) << 1);
      const bf16x8_t vv = *(const bf16x8_t*)&SM[rl * 128 + sc * 8];
      *(bf16x8_t*)&C[(long)(m0 + rl) * 128 + chunk * 8] = vv;
    }
  }
#undef ASH
#undef BSH
}

// ---------------------------------------------------------------------------
__global__ __launch_bounds__(256) void cast_bias_kernel(
    const float* __restrict__ x, const float* __restrict__ Wb,
    const float* __restrict__ bb, bf16_t* __restrict__ x_bf,
    float* __restrict__ biases) {
  const int r = blockIdx.x * 4 + (threadIdx.x >> 6);
  const int l = threadIdx.x & 63;
  const float* xr = x + (long)r * 1024;
  bf16_t* orow = x_bf + (long)r * 1024;
  float s = 0.f;
#pragma unroll
  for (int i = 0; i < 4; ++i) {
    const int off = l * 4 + i * 256;
    const float4 v = *(const float4*)(xr + off);
    const float4 w = *(const float4*)(Wb + off);
    s += v.x * w.x + v.y * w.y + v.z * w.z + v.w * w.w;
    bf16x4_t o;
    o[0] = (bf16_t)v.x; o[1] = (bf16_t)v.y; o[2] = (bf16_t)v.z; o[3] = (bf16_t)v.w;
    *(bf16x4_t*)(orow + off) = o;
  }
#pragma unroll
  for (int off = 1; off < 64; off <<= 1) s += __shfl_xor(s, off);
  if (l == 0) biases[r] = s + bb[0];
}

// batched transpose-cast: Wv, W1 (1024x1024) and Wk, Wq (1024x64) in 1 launch
__global__ __launch_bounds__(256) void transpose_all(
    const float* __restrict__ Wk, const float* __restrict__ Wq,
    const float* __restrict__ Wv, const float* __restrict__ W1,
    bf16_t* __restrict__ Wkqt, bf16_t* __restrict__ Wvt,
    bf16_t* __restrict__ W1t) {
  int b = blockIdx.x;
  const float* in;
  bf16_t* out;
  int R, C, c0, r0;
  if (b < 1024) {
    in = Wv; out = Wvt; R = 1024; C = 1024;
    c0 = (b & 31) * 32; r0 = (b >> 5) * 32;
  } else if (b < 2048) {
    b -= 1024; in = W1; out = W1t; R = 1024; C = 1024;
    c0 = (b & 31) * 32; r0 = (b >> 5) * 32;
  } else if (b < 2112) {
    b -= 2048; in = Wk; out = Wkqt; R = 1024; C = 64;
    c0 = (b & 1) * 32; r0 = (b >> 1) * 32;
  } else {
    b -= 2112; in = Wq; out = Wkqt + 64 * 1024; R = 1024; C = 64;
    c0 = (b & 1) * 32; r0 = (b >> 1) * 32;
  }
  __shared__ float t[32][33];
  const int tx = threadIdx.x & 31, ty = threadIdx.x >> 5;
#pragma unroll
  for (int i = 0; i < 4; ++i) {
    const int rl = ty * 4 + i;
    t[rl][tx] = in[(long)(r0 + rl) * C + c0 + tx];
  }
  __syncthreads();
#pragma unroll
  for (int i = 0; i < 4; ++i) {
    const int rl = ty * 4 + i;
    out[(long)(c0 + rl) * R + r0 + tx] = (bf16_t)t[tx][rl];
  }
}

// wave-per-row LayerNorm: res = bf16(LN(x+attn)*g+be)
__global__ __launch_bounds__(256) void ln1_kernel(
    const bf16_t* __restrict__ x, const bf16_t* __restrict__ attn,
    const float* __restrict__ g, const float* __restrict__ be,
    bf16_t* __restrict__ res) {
  const int w = threadIdx.x >> 6, l = threadIdx.x & 63;
  const long r = (long)blockIdx.x * 4 + w;
  const bf16_t* xr = x + r * 1024;
  const bf16_t* ar = attn + r * 1024;
  float y[16];
  float s = 0.f, ss = 0.f;
#pragma unroll
  for (int h = 0; h < 2; ++h) {
    const int base = h * 512 + l * 8;
    const bf16x8_t xv = *(const bf16x8_t*)(xr + base);
    const bf16x8_t av = *(const bf16x8_t*)(ar + base);
#pragma unroll
    for (int j = 0; j < 8; ++j) {
      const float yy = (float)xv[j] + (float)av[j];
      y[h * 8 + j] = yy;
      s += yy; ss += yy * yy;
    }
  }
#pragma unroll
  for (int off = 1; off < 64; off <<= 1) {
    s += __shfl_xor(s, off);
    ss += __shfl_xor(ss, off);
  }
  const float mean = s * (1.0f / 1024.0f);
  const float rs = rsqrtf(ss * (1.0f / 1024.0f) - mean * mean + 1e-5f);
  bf16_t* orow = res + r * 1024;
#pragma unroll
  for (int h = 0; h < 2; ++h) {
    const int base = h * 512 + l * 8;
    bf16x8_t o;
#pragma unroll
    for (int j = 0; j < 8; ++j)
      o[j] = (bf16_t)((y[h * 8 + j] - mean) * rs * g[base + j] + be[base + j]);
    *(bf16x8_t*)(orow + base) = o;
  }
}

// wave-per-row: out = LN(res + h), fp32 out
__global__ __launch_bounds__(256) void ln2_kernel(
    const bf16_t* __restrict__ res, const bf16_t* __restrict__ hh,
    float* __restrict__ out) {
  const int w = threadIdx.x >> 6, l = threadIdx.x & 63;
  const long r = (long)blockIdx.x * 4 + w;
  const bf16_t* rr = res + r * 1024;
  const bf16_t* hr = hh + r * 1024;
  float y[16];
  float s = 0.f, ss = 0.f;
#pragma unroll
  for (int h = 0; h < 2; ++h) {
    const int base = h * 512 + l * 8;
    const bf16x8_t rv = *(const bf16x8_t*)(rr + base);
    const bf16x8_t hv = *(const bf16x8_t*)(hr + base);
#pragma unroll
    for (int j = 0; j < 8; ++j) {
      const float yy = (float)rv[j] + (float)hv[j];
      y[h * 8 + j] = yy;
      s += yy; ss += yy * yy;
    }
  }
#pragma unroll
  for (int off = 1; off < 64; off <<= 1) {
    s += __shfl_xor(s, off);
    ss += __shfl_xor(ss, off);
  }
  const float mean = s * (1.0f / 1024.0f);
  const float rs = rsqrtf(ss * (1.0f / 1024.0f) - mean * mean + 1e-5f);
  float* orow = out + r * 1024;
#pragma unroll
  for (int h = 0; h < 2; ++h) {
    const int base = h * 512 + l * 8;
    float4 o1, o2;
    o1.x = (y[h * 8 + 0] - mean) * rs; o1.y = (y[h * 8 + 1] - mean) * rs;
    o1.z = (y[h * 8 + 2] - mean) * rs; o1.w = (y[h * 8 + 3] - mean) * rs;
    o2.x = (y[h * 8 + 4] - mean) * rs; o2.y = (y[h * 8 + 5] - mean) * rs;
    o2.z = (y[h * 8 + 6] - mean) * rs; o2.w = (y[h * 8 + 7] - mean) * rs;
    *(float4*)(orow + base) = o1;
    *(float4*)(orow + base + 4) = o2;
  }
}

// ---------------------------------------------------------------------------
extern "C" void kernel_launch(void* const* d_in, const int* in_sizes, int n_in,
                              void* d_out, int out_size, void* d_ws, size_t ws_size,
                              hipStream_t stream) {
  const float* x   = (const float*)d_in[0];
  const float* Wk  = (const float*)d_in[1];
  const float* bk  = (const float*)d_in[2];
  const float* Wq  = (const float*)d_in[3];
  const float* bq  = (const float*)d_in[4];
  const float* Wv  = (const float*)d_in[5];
  const float* bv  = (const float*)d_in[6];
  const float* Wb  = (const float*)d_in[7];
  const float* bb  = (const float*)d_in[8];
  const float* W1  = (const float*)d_in[9];
  const float* b1  = (const float*)d_in[10];
  const float* g1  = (const float*)d_in[11];
  const float* be1 = (const float*)d_in[12];
  float* out = (float*)d_out;

  char* ws = (char*)d_ws;
  bf16_t* x_bf    = (bf16_t*)(ws + 0);           //  32 MB  [16384][1024]
  bf16_t* vt_bf   = (bf16_t*)(ws + 33554432);    //  32 MB  V^T [1024][16384]
  bf16_t* kq_bf   = (bf16_t*)(ws + 67108864);    //   4 MB  [16384][128]
  bf16_t* Wkqt    = (bf16_t*)(ws + 71303168);    // 256 KB  [128][1024]
  bf16_t* Wvt     = (bf16_t*)(ws + 71565312);    //   2 MB
  bf16_t* W1t     = (bf16_t*)(ws + 73662464);    //   2 MB
  float*  biases  = (float*) (ws + 75759616);    //  64 KB
  bf16_t* scores  = (bf16_t*)(ws + 75825152);    //  64 MB  [8][2048][2048]
  bf16_t* attn_bf = (bf16_t*)(ws + 142934016);   //  32 MB  [8][2048][1024]
  bf16_t* res_bf  = (bf16_t*)(ws + 176488448);   //  32 MB
  bf16_t* h_bf    = attn_bf;                     // alias: attn dead after ln1

  cast_bias_kernel<<<4096, 256, 0, stream>>>(x, Wb, bb, x_bf, biases);
  transpose_all<<<2176, 256, 0, stream>>>(Wk, Wq, Wv, W1, Wkqt, Wvt, W1t);

  // keys|queries: [16384][128], thin-N kernel, 256 blocks
  kq_thin<<<256, 256, 0, stream>>>(x_bf, Wkqt, kq_bf, bk, bq);

  // V^T = Wv^T @ x^T (+bv row bias): EXPERIMENT 256x128 / 2 blocks/CU
  gemm128n<1, 1><<<dim3(128, 4), 512, 0, stream>>>(
      Wvt, x_bf, vt_bf, 1024, 1024, 1024, 16384, bv);

  // scores = sigmoid(keys.queries^T + bias_i)
  scores128<<<dim3(16, 16, 8), 256, 0, stream>>>(kq_bf, scores, biases);

  // attn = scores @ V: CONTROL kernel (R12 schedule)
  gemm256p<3><<<dim3(4, 8, 8), 512, 0, stream>>>(
      scores, vt_bf, attn_bf, 2048, 2048, 16384, 1024,
      2048L * 2048, 2048, 2048L * 1024, nullptr);

  // res = bf16(LN(x+attn)*g1+be1)
  ln1_kernel<<<4096, 256, 0, stream>>>(x_bf, attn_bf, g1, be1, res_bf);

  // h = relu(res @ W1 + b1): EXPERIMENT 256x128 / 2 blocks/CU
  gemm128n<4, 0><<<dim3(8, 64), 512, 0, stream>>>(
      res_bf, W1t, h_bf, 1024, 1024, 1024, 1024, b1);

  // out = LN(res + h)
  ln2_kernel<<<4096, 256, 0, stream>>>(res_bf, h_bf, out);
}